// Round 5
// baseline (459.003 us; speedup 1.0000x reference)
//
#include <hip/hip_runtime.h>

// ---------------------------------------------------------------------------
// BasicTransformerBlock on MI355X (gfx950).
// R14: single-variable experiment on the top dispatch. Ledger: R9=463,
// R10=458, R13=459 -> the whole scheduling axis (2buf/3buf/counted-vmcnt)
// is null at fixed {tile, waves/CU}; what moved dispatches was staged-bytes
// -per-FLOP and wave count (R10 GEGLU -25% waves -> +7%; R11 smaller tiles
// -> +6%). New: GEGLU 128x64-dual -> 128x128-dual at EQUAL wave occupancy
// (8 waves x 2 blocks/CU = 16 waves/CU, same as 4x4): -25% staged B/FLOP,
// half the barrier groups. Template already general; launch-config change
// only. Everything else frozen at R13.
// ---------------------------------------------------------------------------

typedef _Float16 half8 __attribute__((ext_vector_type(8)));
typedef float f32x4 __attribute__((ext_vector_type(4)));

__device__ __forceinline__ f32x4 mfma16(half8 a, half8 b, f32x4 c) {
  return __builtin_amdgcn_mfma_f32_16x16x32_f16(a, b, c, 0, 0, 0);
}

__device__ __forceinline__ void gload16(const _Float16* g, _Float16* l) {
  __builtin_amdgcn_global_load_lds(
      (const __attribute__((address_space(1))) void*)g,
      (__attribute__((address_space(3))) void*)l, 16, 0, 0);
}

template <int N>
__device__ __forceinline__ void wait_vmcnt() {
  if constexpr (N == 0)
    asm volatile("s_waitcnt vmcnt(0)" ::: "memory");
  else if constexpr (N == 1)
    asm volatile("s_waitcnt vmcnt(1)" ::: "memory");
  else if constexpr (N == 2)
    asm volatile("s_waitcnt vmcnt(2)" ::: "memory");
  else if constexpr (N == 3)
    asm volatile("s_waitcnt vmcnt(3)" ::: "memory");
  else if constexpr (N == 4)
    asm volatile("s_waitcnt vmcnt(4)" ::: "memory");
  else
    static_assert(N <= 4, "add a case");
}

// ---------------- fused prep: 10 weight transposes + enc cvt + LN1 ---------
struct PrepArgs {
  const float* src[10];
  _Float16* dst[10];
  int K[10], N[10], base[10];
  const float* enc;
  _Float16* ench;
  int encBase, nEnc;
  const float* x;
  const float* ln1g;
  const float* ln1b;
  _Float16* hbuf;
  int lnBase;  // first block index of LN rows (8192 rows follow)
};

__global__ __launch_bounds__(256)
void prep_all(PrepArgs pa) {
  __shared__ float tile[32][33];
  const int bid = blockIdx.x;
  const int tx = threadIdx.x, ty = threadIdx.y;
  const int t = ty * 32 + tx;
  if (bid >= pa.lnBase) {
    // -------- LayerNorm1 row --------
    const int row = bid - pa.lnBase;
    const float* xr = pa.x + (size_t)row * 512;
    float v0 = xr[t], v1 = xr[t + 256];
    float s1 = v0 + v1, s2 = v0 * v0 + v1 * v1;
    #pragma unroll
    for (int m = 32; m >= 1; m >>= 1) {
      s1 += __shfl_xor(s1, m);
      s2 += __shfl_xor(s2, m);
    }
    __shared__ float red[8];
    if ((t & 63) == 0) { red[t >> 6] = s1; red[4 + (t >> 6)] = s2; }
    __syncthreads();
    s1 = red[0] + red[1] + red[2] + red[3];
    s2 = red[4] + red[5] + red[6] + red[7];
    const float mu = s1 * (1.0f / 512.0f);
    const float var = s2 * (1.0f / 512.0f) - mu * mu;
    const float rs = rsqrtf(var + 1e-5f);
    pa.hbuf[(size_t)row * 512 + t] =
        (_Float16)((v0 - mu) * rs * pa.ln1g[t] + pa.ln1b[t]);
    pa.hbuf[(size_t)row * 512 + t + 256] =
        (_Float16)((v1 - mu) * rs * pa.ln1g[t + 256] + pa.ln1b[t + 256]);
    return;
  }
  if (bid >= pa.encBase) {
    const int i = (bid - pa.encBase) * 256 + t;
    if (i < pa.nEnc) pa.ench[i] = (_Float16)pa.enc[i];
    return;
  }
  int mi = 0;
  #pragma unroll
  for (int j = 1; j < 10; j++)
    if (bid >= pa.base[j]) mi = j;
  const int K = pa.K[mi], N = pa.N[mi];
  const int rel = bid - pa.base[mi];
  const int ntiles = N >> 5;
  const int bx = rel % ntiles, by = rel / ntiles;
  const float* src = pa.src[mi];
  _Float16* dst = pa.dst[mi];
  const int n0 = bx * 32, k0 = by * 32;
  #pragma unroll
  for (int j = ty; j < 32; j += 8)
    tile[j][tx] = src[(size_t)(k0 + j) * N + n0 + tx];
  __syncthreads();
  #pragma unroll
  for (int j = ty; j < 32; j += 8)
    dst[(size_t)(n0 + j) * K + k0 + tx] = (_Float16)tile[tx][j];
}

// ---------------- V transpose: [b*S+s][h*64+d] -> [(bh*64)+d][s] -----------
__global__ __launch_bounds__(256)
void vt_kernel(const _Float16* __restrict__ src, _Float16* __restrict__ dst,
               int S, int srcStride, int dstStride) {
  __shared__ _Float16 tile[32][33];
  const int tx = threadIdx.x, ty = threadIdx.y;  // (32,8)
  const int s0 = blockIdx.x * 32, d0 = blockIdx.y * 32, bh = blockIdx.z;
  const int b = bh >> 3, h = bh & 7;
  const _Float16* sp = src + (size_t)b * S * srcStride + h * 64 + d0;
  #pragma unroll
  for (int j = ty; j < 32; j += 8) {
    int s = s0 + j; if (s >= S) s = S - 1;
    tile[j][tx] = sp[(size_t)s * srcStride + tx];
  }
  __syncthreads();
  _Float16* dp = dst + ((size_t)bh * 64 + d0) * dstStride + s0;
  #pragma unroll
  for (int j = ty; j < 32; j += 8)
    dp[(size_t)j * dstStride + tx] = tile[tx][j];
}

// ---------------- LayerNorm (row=512), fp32 in -> f16 out ------------------
__global__ __launch_bounds__(256)
void ln_kernel(const float* __restrict__ x, const float* __restrict__ g,
               const float* __restrict__ b, _Float16* __restrict__ out) {
  const int row = blockIdx.x, t = threadIdx.x;
  const float* xr = x + (size_t)row * 512;
  float v0 = xr[t], v1 = xr[t + 256];
  float s1 = v0 + v1, s2 = v0 * v0 + v1 * v1;
  #pragma unroll
  for (int m = 32; m >= 1; m >>= 1) {
    s1 += __shfl_xor(s1, m);
    s2 += __shfl_xor(s2, m);
  }
  __shared__ float red[8];
  if ((t & 63) == 0) { red[t >> 6] = s1; red[4 + (t >> 6)] = s2; }
  __syncthreads();
  s1 = red[0] + red[1] + red[2] + red[3];
  s2 = red[4] + red[5] + red[6] + red[7];
  const float mu = s1 * (1.0f / 512.0f);
  const float var = s2 * (1.0f / 512.0f) - mu * mu;
  const float rs = rsqrtf(var + 1e-5f);
  out[(size_t)row * 512 + t] = (_Float16)((v0 - mu) * rs * g[t] + b[t]);
  out[(size_t)row * 512 + t + 256] =
      (_Float16)((v1 - mu) * rs * g[t + 256] + b[t + 256]);
}

// ---------------- GEMM: C = A[M,K] @ BT[N,K]^T, XCD swizzle ----------------
// PIPE=0: R9 2-buffer __syncthreads loop. PIPE=1: R10 3-buffer counted-vmcnt.
// EPI 0: f16 store. EPI 1: Cf = resid + acc + bias. EPI 2: GEGLU dual.
template <int EPI, int GWM, int GWN, int WM, int WN, int MW, int SWZ,
          int PIPE>
__global__ __launch_bounds__(GWM * GWN * 64, MW)
void gemm_bt(const _Float16* __restrict__ A, const _Float16* __restrict__ BT,
             int M, int N, int K, int lda, int ldb, int ldc,
             _Float16* Ch, float* Cf,
             const float* __restrict__ bias, const float* resid) {
  constexpr int NW = GWM * GWN;
  constexpr int BM = GWM * WM * 16;
  constexpr int BN = GWN * WN * 16;
  constexpr int NBUF = PIPE ? 3 : 2;
  // per-thread global_load_lds per stage (uniform across threads)
  constexpr int LPT = (BM / 16) / NW + ((BN / 16) / NW) * ((EPI == 2) ? 2 : 1);
  __shared__ __align__(16) _Float16 As[NBUF][4 * BM * 8];
  __shared__ __align__(16) _Float16 Bs[NBUF][4 * BN * 8];
  __shared__ __align__(16) _Float16 Bs2[(EPI == 2) ? NBUF : 1]
                                      [(EPI == 2) ? 4 * BN * 8 : 8];

  const int t = threadIdx.x;
  const int NNB = (N + BN - 1) / BN;
  int bm, bn;
  if constexpr (SWZ) {
    const int MG = (M / BM) >> 3;
    const int xcd = blockIdx.x & 7;
    const int s = blockIdx.x >> 3;
    bm = xcd * MG + s % MG;
    bn = s / MG;
  } else {
    bn = blockIdx.x % NNB;
    bm = blockIdx.x / NNB;
  }
  const int m0 = bm * BM, n0 = bn * BN;
  const int lane = t & 63, wv = t >> 6;
  const int quad = lane >> 4, l15 = lane & 15;
  const int wm = wv / GWN, wn = wv % GWN;

  f32x4 zero4 = {0.f, 0.f, 0.f, 0.f};
  f32x4 acc[WM][WN];
  f32x4 acc2[(EPI == 2) ? WM : 1][(EPI == 2) ? WN : 1];
  #pragma unroll
  for (int mi = 0; mi < WM; mi++)
    #pragma unroll
    for (int ni = 0; ni < WN; ni++) acc[mi][ni] = zero4;
  if constexpr (EPI == 2) {
    #pragma unroll
    for (int mi = 0; mi < WM; mi++)
      #pragma unroll
      for (int ni = 0; ni < WN; ni++) acc2[mi][ni] = zero4;
  }

  auto stageAll = [&](int k0, int pb) {
    #pragma unroll
    for (int c = wv; c < BM / 16; c += NW) {
      const int s = c * 64 + lane;
      const int q = s / BM;
      const int r = s % BM;
      int rg = m0 + r; if (rg >= M) rg = M - 1;
      gload16(A + (size_t)rg * lda + k0 + q * 8, &As[pb][c * 512]);
    }
    #pragma unroll
    for (int c = wv; c < BN / 16; c += NW) {
      const int s = c * 64 + lane;
      const int q = s / BN;
      const int r = s % BN;
      gload16(BT + (size_t)(n0 + r) * ldb + k0 + q * 8, &Bs[pb][c * 512]);
      if constexpr (EPI == 2)
        gload16(BT + (size_t)(2048 + n0 + r) * ldb + k0 + q * 8,
                &Bs2[pb][c * 512]);
    }
  };

  auto computeTile = [&](int cur) {
    half8 fa[WM], fb[WN], fb2[(EPI == 2) ? WN : 1];
    #pragma unroll
    for (int mi = 0; mi < WM; mi++)
      fa[mi] = *(const half8*)(&As[cur]
          [((size_t)quad * BM + wm * WM * 16 + mi * 16 + l15) * 8]);
    #pragma unroll
    for (int ni = 0; ni < WN; ni++) {
      fb[ni] = *(const half8*)(&Bs[cur]
          [((size_t)quad * BN + wn * WN * 16 + ni * 16 + l15) * 8]);
      if constexpr (EPI == 2)
        fb2[ni] = *(const half8*)(&Bs2[cur]
            [((size_t)quad * BN + wn * WN * 16 + ni * 16 + l15) * 8]);
    }
    if constexpr (PIPE) __builtin_amdgcn_s_setprio(1);
    #pragma unroll
    for (int mi = 0; mi < WM; mi++)
      #pragma unroll
      for (int ni = 0; ni < WN; ni++) {
        acc[mi][ni] = mfma16(fa[mi], fb[ni], acc[mi][ni]);
        if constexpr (EPI == 2)
          acc2[mi][ni] = mfma16(fa[mi], fb2[ni], acc2[mi][ni]);
      }
    if constexpr (PIPE) __builtin_amdgcn_s_setprio(0);
  };

  const int NIT = K >> 5;
  if constexpr (PIPE) {
    // 3-buffer stage-ahead-2, counted vmcnt (R10 form).
    stageAll(0, 0);
    if (NIT > 1) stageAll(32, 1);
    int cur = 0, pre = 2;
    for (int it = 0; it < NIT; ++it) {
      if (it + 1 < NIT) wait_vmcnt<LPT>();
      else wait_vmcnt<0>();
      __builtin_amdgcn_s_barrier();
      __builtin_amdgcn_sched_barrier(0);
      computeTile(cur);
      asm volatile("s_waitcnt lgkmcnt(0)" ::: "memory");
      __builtin_amdgcn_sched_barrier(0);
      __builtin_amdgcn_s_barrier();
      if (it + 2 < NIT) stageAll((it + 2) << 5, pre);
      cur = (cur == 2) ? 0 : cur + 1;
      pre = (pre == 2) ? 0 : pre + 1;
    }
  } else {
    // 2-buffer __syncthreads loop (R9 form).
    stageAll(0, 0);
    __syncthreads();
    for (int it = 0; it < NIT; ++it) {
      const int cur = it & 1;
      if (it + 1 < NIT) stageAll((it + 1) << 5, cur ^ 1);
      computeTile(cur);
      __syncthreads();
    }
  }

  #pragma unroll
  for (int mi = 0; mi < WM; mi++) {
    const int rbase = m0 + wm * WM * 16 + mi * 16 + quad * 4;
    #pragma unroll
    for (int r = 0; r < 4; r++) {
      const int row = rbase + r;
      if (row >= M) continue;
      #pragma unroll
      for (int ni = 0; ni < WN; ni++) {
        const int col = n0 + wn * WN * 16 + ni * 16 + l15;
        const float v = acc[mi][ni][r];
        if constexpr (EPI == 0) {
          Ch[(size_t)row * ldc + col] = (_Float16)v;
        } else if constexpr (EPI == 1) {
          Cf[(size_t)row * ldc + col] =
              resid[(size_t)row * ldc + col] + v + bias[col];
        } else {
          const float u = v + bias[col];
          const float gg = acc2[mi][ni][r] + bias[col + 2048];
          const float ge = 0.5f * gg * (1.0f + erff(gg * 0.70710678118f));
          Ch[(size_t)row * ldc + col] = (_Float16)(u * ge);
        }
      }
    }
  }
}

// ---------------- flash attention v2, 3-buffer counted-vmcnt pipeline ------
__global__ __launch_bounds__(256)
void attn2(const _Float16* __restrict__ Q, const _Float16* __restrict__ K,
           const _Float16* __restrict__ VT, _Float16* __restrict__ O,
           int qStride, int kStride, long kBatchStride,
           int vtStride, int Sk) {
  __shared__ __align__(16) _Float16 KsL[3][2048];
  __shared__ __align__(16) _Float16 VTsL[3][2048];
  __shared__ __align__(16) _Float16 Ps[4][2][16][40];

  const int t = threadIdx.x;
  const int w = t >> 6, lane = t & 63, quad = lane >> 4, l15 = lane & 15;
  const int bh = blockIdx.y, b = bh >> 3, h = bh & 7;
  const int q0 = blockIdx.x * 128 + w * 32;

  const _Float16 qscale = (_Float16)(0.125f * 1.44269504f);
  half8 qf[2][2];
  #pragma unroll
  for (int mi = 0; mi < 2; mi++)
    #pragma unroll
    for (int c = 0; c < 2; c++) {
      const _Float16* qp = Q +
          (size_t)(b * 1024 + q0 + mi * 16 + l15) * qStride +
          h * 64 + c * 32 + quad * 8;
      half8 v = *(const half8*)qp;
      #pragma unroll
      for (int j = 0; j < 8; j++) v[j] *= qscale;
      qf[mi][c] = v;
    }

  f32x4 zero4 = {0.f, 0.f, 0.f, 0.f};
  f32x4 oa[2][4];
  float psum[2][4];
  #pragma unroll
  for (int mi = 0; mi < 2; mi++) {
    #pragma unroll
    for (int nt = 0; nt < 4; nt++) oa[mi][nt] = zero4;
    #pragma unroll
    for (int r = 0; r < 4; r++) psum[mi][r] = 0.f;
  }

  const _Float16* kp = K + (size_t)b * kBatchStride + h * 64;
  const _Float16* vtp = VT + (size_t)bh * 64 * vtStride;
  const int ksk = t & 31, kc = t >> 7, kqd = (t >> 5) & 3;
  const int vd = t & 63, vqd = t >> 6;

  auto stageKV = [&](int skb, int pb) {
    int skc = skb + ksk; if (skc >= Sk) skc = Sk - 1;
    gload16(kp + (size_t)skc * kStride + kc * 32 + kqd * 8, &KsL[pb][t * 8]);
    gload16(vtp + (size_t)vd * vtStride + skb + vqd * 8, &VTsL[pb][t * 8]);
  };

  const int NITa = (Sk + 31) >> 5;
  stageKV(0, 0);
  if (NITa > 1) stageKV(32, 1);

  int cur = 0, pre = 2;
  int it = 0;
  for (int skb = 0; skb < Sk; skb += 32, ++it) {
    if (it + 1 < NITa) wait_vmcnt<2>();
    else wait_vmcnt<0>();
    __builtin_amdgcn_s_barrier();
    __builtin_amdgcn_sched_barrier(0);

    const bool tail = (skb + 32 > Sk);
    #pragma unroll
    for (int mi = 0; mi < 2; mi++) {
      #pragma unroll
      for (int ct = 0; ct < 2; ct++) {
        f32x4 s = zero4;
        half8 kb0 = *(const half8*)(&KsL[cur][(quad * 32 + ct * 16 + l15) * 8]);
        half8 kb1 =
            *(const half8*)(&KsL[cur][(128 + quad * 32 + ct * 16 + l15) * 8]);
        s = mfma16(qf[mi][0], kb0, s);
        s = mfma16(qf[mi][1], kb1, s);
        if (tail) {
          const bool valid = (skb + ct * 16 + l15) < Sk;
          #pragma unroll
          for (int r = 0; r < 4; r++)
            if (!valid) s[r] = -__builtin_inff();
        }
        #pragma unroll
        for (int r = 0; r < 4; r++) {
          const float e = exp2f(s[r]);
          psum[mi][r] += e;
          Ps[w][mi][quad * 4 + r][ct * 16 + l15] = (_Float16)e;
        }
      }
    }
    #pragma unroll
    for (int mi = 0; mi < 2; mi++) {
      const half8 pf = *(const half8*)(&Ps[w][mi][l15][quad * 8]);
      #pragma unroll
      for (int nt = 0; nt < 4; nt++) {
        const half8 vf =
            *(const half8*)(&VTsL[cur][(quad * 64 + nt * 16 + l15) * 8]);
        oa[mi][nt] = mfma16(pf, vf, oa[mi][nt]);
      }
    }

    asm volatile("s_waitcnt lgkmcnt(0)" ::: "memory");
    __builtin_amdgcn_sched_barrier(0);
    __builtin_amdgcn_s_barrier();
    if (it + 2 < NITa) stageKV(skb + 64, pre);
    cur = (cur == 2) ? 0 : cur + 1;
    pre = (pre == 2) ? 0 : pre + 1;
  }

  #pragma unroll
  for (int mi = 0; mi < 2; mi++)
    #pragma unroll
    for (int r = 0; r < 4; r++) {
      #pragma unroll
      for (int mm = 1; mm < 16; mm <<= 1)
        psum[mi][r] += __shfl_xor(psum[mi][r], mm);
      psum[mi][r] = 1.0f / psum[mi][r];
    }

  #pragma unroll
  for (int mi = 0; mi < 2; mi++)
    #pragma unroll
    for (int nt = 0; nt < 4; nt++)
      #pragma unroll
      for (int r = 0; r < 4; r++) {
        const size_t row = (size_t)(b * 1024 + q0 + mi * 16 + quad * 4 + r);
        O[row * 512 + h * 64 + nt * 16 + l15] =
            (_Float16)(oa[mi][nt][r] * psum[mi][r]);
      }
}

// ---------------------------------------------------------------------------
extern "C" void kernel_launch(void* const* d_in, const int* in_sizes, int n_in,
                              void* d_out, int out_size, void* d_ws,
                              size_t ws_size, hipStream_t stream) {
  const float* x    = (const float*)d_in[0];
  const float* enc  = (const float*)d_in[1];
  const float* ln1g = (const float*)d_in[2];
  const float* ln1b = (const float*)d_in[3];
  const float* wq1  = (const float*)d_in[4];
  const float* wk1  = (const float*)d_in[5];
  const float* wv1  = (const float*)d_in[6];
  const float* wo1  = (const float*)d_in[7];
  const float* bo1  = (const float*)d_in[8];
  const float* ln2g = (const float*)d_in[9];
  const float* ln2b = (const float*)d_in[10];
  const float* wq2  = (const float*)d_in[11];
  const float* wk2  = (const float*)d_in[12];
  const float* wv2  = (const float*)d_in[13];
  const float* wo2  = (const float*)d_in[14];
  const float* bo2  = (const float*)d_in[15];
  const float* ln3g = (const float*)d_in[16];
  const float* ln3b = (const float*)d_in[17];
  const float* wg   = (const float*)d_in[18];
  const float* bg   = (const float*)d_in[19];
  const float* wf   = (const float*)d_in[20];
  const float* bfp  = (const float*)d_in[21];
  float* out = (float*)d_out;

  char* ws = (char*)d_ws;
  _Float16* qkvT  = (_Float16*)(ws + 0);         // [1536,512]
  _Float16* q2T   = (_Float16*)(ws + 1572864);   // [512,512]
  _Float16* kv2T  = (_Float16*)(ws + 2097152);   // [1024,768]
  _Float16* wo1T  = (_Float16*)(ws + 3670016);   // [512,512]
  _Float16* wo2T  = (_Float16*)(ws + 4194304);   // [512,512]
  _Float16* wgT   = (_Float16*)(ws + 4718592);   // [4096,512]
  _Float16* wfT   = (_Float16*)(ws + 8912896);   // [512,2048]
  _Float16* hbuf  = (_Float16*)(ws + 11010048);  // [8192,512] (VTself in attn1)
  _Float16* qkv   = (_Float16*)(ws + 19398656);  // [8192,1536]
  _Float16* q2b   = (_Float16*)(ws + 44564480);  // [8192,512]
  _Float16* kv2b  = (_Float16*)(ws + 52953088);  // [616,1024]
  _Float16* attnb = (_Float16*)(ws + 54214656);  // [8192,512]
  _Float16* ench  = (_Float16*)(ws + 62603264);  // [616,768]
  _Float16* ffb   = (_Float16*)(ws + 19398656);  // [8192,2048] aliases qkv+q2b
  _Float16* VTself = hbuf;                       // [4096,1024]
  _Float16* VTc   = (_Float16*)(ws + 62603264);  // [4096,96] over ench (dead
                                                 // after kv2 GEMM)

  // ---- fused prep: weights + enc + LN1 (one launch) ----
  PrepArgs pa;
  const float* srcs[10] = {wq1, wk1, wv1, wo1, wq2, wk2, wv2, wo2, wg, wf};
  _Float16* dsts[10] = {qkvT, qkvT + 512 * 512, qkvT + 1024 * 512, wo1T, q2T,
                        kv2T, kv2T + 512 * 768, wo2T, wgT, wfT};
  const int Ks[10] = {512, 512, 512, 512, 512, 768, 768, 512, 512, 2048};
  const int Ns[10] = {512, 512, 512, 512, 512, 512, 512, 512, 4096, 512};
  int base = 0;
  for (int i = 0; i < 10; i++) {
    pa.src[i] = srcs[i]; pa.dst[i] = dsts[i];
    pa.K[i] = Ks[i]; pa.N[i] = Ns[i]; pa.base[i] = base;
    base += (Ks[i] >> 5) * (Ns[i] >> 5);
  }
  pa.enc = enc; pa.ench = ench; pa.encBase = base; pa.nEnc = 473088;
  base += (473088 + 255) / 256;
  pa.x = x; pa.ln1g = ln1g; pa.ln1b = ln1b; pa.hbuf = hbuf; pa.lnBase = base;
  base += 8192;
  prep_all<<<base, dim3(32, 8), 0, stream>>>(pa);

  const dim3 tb(32, 8);

  // ---- self-attention block ----
  gemm_bt<0, 2, 2, 4, 4, 3, 1, 1><<<768, 256, 0, stream>>>(
      hbuf, qkvT, 8192, 1536, 512, 512, 512, 1536,
      qkv, nullptr, nullptr, nullptr);
  vt_kernel<<<dim3(32, 2, 64), tb, 0, stream>>>(qkv + 1024, VTself, 1024,
                                                1536, 1024);
  attn2<<<dim3(8, 64), 256, 0, stream>>>(qkv, qkv + 512, VTself, attnb,
                                         1536, 1536, (long)1024 * 1536,
                                         1024, 1024);
  gemm_bt<1, 1, 4, 4, 2, 4, 1, 1><<<512, 256, 0, stream>>>(
      attnb, wo1T, 8192, 512, 512, 512, 512, 512, nullptr, out, bo1, x);

  // ---- cross-attention block ----
  ln_kernel<<<8192, 256, 0, stream>>>(out, ln2g, ln2b, hbuf);
  gemm_bt<0, 1, 4, 4, 2, 4, 1, 1><<<512, 256, 0, stream>>>(
      hbuf, q2T, 8192, 512, 512, 512, 512, 512,
      q2b, nullptr, nullptr, nullptr);
  gemm_bt<0, 1, 4, 4, 2, 4, 0, 1><<<80, 256, 0, stream>>>(
      ench, kv2T, 616, 1024, 768, 768, 768, 1024,
      kv2b, nullptr, nullptr, nullptr);
  vt_kernel<<<dim3(3, 2, 64), tb, 0, stream>>>(kv2b + 512, VTc, 77, 1024, 96);
  attn2<<<dim3(8, 64), 256, 0, stream>>>(q2b, kv2b, VTc, attnb,
                                         512, 1024, (long)77 * 1024, 96, 77);
  gemm_bt<1, 1, 4, 4, 2, 4, 1, 1><<<512, 256, 0, stream>>>(
      attnb, wo2T, 8192, 512, 512, 512, 512, 512, nullptr, out, bo2, out);

  // ---- GEGLU feed-forward ----
  ln_kernel<<<8192, 256, 0, stream>>>(out, ln3g, ln3b, hbuf);
  // GEGLU: 128x128-dual, 8 waves (512 thr), 2 blocks/CU = 16 waves/CU
  // (same wave count as R9's 4x4; -25% staged bytes/FLOP). Grid 64x16=1024.
  gemm_bt<2, 2, 4, 4, 2, 4, 1, 0><<<1024, 512, 0, stream>>>(
      hbuf, wgT, 8192, 2048, 512, 512, 512, 2048,
      ffb, nullptr, bg, nullptr);
  gemm_bt<1, 1, 4, 4, 2, 4, 1, 1><<<512, 256, 0, stream>>>(
      ffb, wfT, 8192, 512, 2048, 2048, 2048, 512,
      nullptr, out, bfp, out);
}

// Round 6
// 443.504 us; speedup vs baseline: 1.0349x; 1.0349x over previous
//
#include <hip/hip_runtime.h>

// ---------------------------------------------------------------------------
// BasicTransformerBlock on MI355X (gfx950).
// R15: attn occupancy. GEMM axes are exhausted (R9-R14: schedule null,
// occupancy-at-fixed-tile null, tile +-3%; GEGLU pinned ~85us). attn1 is
// grid-capped: 512 blocks x 4 waves = 8 waves/CU (25%). Restructure attn to
// 8 waves x 16 Q-rows (was 4 x 32): same 128-row block, same per-block K/V
// staging (1 gload16/thread, waves 0-3 stage K, 4-7 stage VT), grid
// unchanged -> 16 waves/CU (2x). Per-wave regs halve. R10 established
// duration ~ 1/occupancy at fixed structure for this family.
// Everything else frozen at R14 (GEGLU 128x128-dual 8-wave kept, 85.0us).
// ---------------------------------------------------------------------------

typedef _Float16 half8 __attribute__((ext_vector_type(8)));
typedef float f32x4 __attribute__((ext_vector_type(4)));

__device__ __forceinline__ f32x4 mfma16(half8 a, half8 b, f32x4 c) {
  return __builtin_amdgcn_mfma_f32_16x16x32_f16(a, b, c, 0, 0, 0);
}

__device__ __forceinline__ void gload16(const _Float16* g, _Float16* l) {
  __builtin_amdgcn_global_load_lds(
      (const __attribute__((address_space(1))) void*)g,
      (__attribute__((address_space(3))) void*)l, 16, 0, 0);
}

template <int N>
__device__ __forceinline__ void wait_vmcnt() {
  if constexpr (N == 0)
    asm volatile("s_waitcnt vmcnt(0)" ::: "memory");
  else if constexpr (N == 1)
    asm volatile("s_waitcnt vmcnt(1)" ::: "memory");
  else if constexpr (N == 2)
    asm volatile("s_waitcnt vmcnt(2)" ::: "memory");
  else if constexpr (N == 3)
    asm volatile("s_waitcnt vmcnt(3)" ::: "memory");
  else if constexpr (N == 4)
    asm volatile("s_waitcnt vmcnt(4)" ::: "memory");
  else
    static_assert(N <= 4, "add a case");
}

// ---------------- fused prep: 10 weight transposes + enc cvt + LN1 ---------
struct PrepArgs {
  const float* src[10];
  _Float16* dst[10];
  int K[10], N[10], base[10];
  const float* enc;
  _Float16* ench;
  int encBase, nEnc;
  const float* x;
  const float* ln1g;
  const float* ln1b;
  _Float16* hbuf;
  int lnBase;  // first block index of LN rows (8192 rows follow)
};

__global__ __launch_bounds__(256)
void prep_all(PrepArgs pa) {
  __shared__ float tile[32][33];
  const int bid = blockIdx.x;
  const int tx = threadIdx.x, ty = threadIdx.y;
  const int t = ty * 32 + tx;
  if (bid >= pa.lnBase) {
    // -------- LayerNorm1 row --------
    const int row = bid - pa.lnBase;
    const float* xr = pa.x + (size_t)row * 512;
    float v0 = xr[t], v1 = xr[t + 256];
    float s1 = v0 + v1, s2 = v0 * v0 + v1 * v1;
    #pragma unroll
    for (int m = 32; m >= 1; m >>= 1) {
      s1 += __shfl_xor(s1, m);
      s2 += __shfl_xor(s2, m);
    }
    __shared__ float red[8];
    if ((t & 63) == 0) { red[t >> 6] = s1; red[4 + (t >> 6)] = s2; }
    __syncthreads();
    s1 = red[0] + red[1] + red[2] + red[3];
    s2 = red[4] + red[5] + red[6] + red[7];
    const float mu = s1 * (1.0f / 512.0f);
    const float var = s2 * (1.0f / 512.0f) - mu * mu;
    const float rs = rsqrtf(var + 1e-5f);
    pa.hbuf[(size_t)row * 512 + t] =
        (_Float16)((v0 - mu) * rs * pa.ln1g[t] + pa.ln1b[t]);
    pa.hbuf[(size_t)row * 512 + t + 256] =
        (_Float16)((v1 - mu) * rs * pa.ln1g[t + 256] + pa.ln1b[t + 256]);
    return;
  }
  if (bid >= pa.encBase) {
    const int i = (bid - pa.encBase) * 256 + t;
    if (i < pa.nEnc) pa.ench[i] = (_Float16)pa.enc[i];
    return;
  }
  int mi = 0;
  #pragma unroll
  for (int j = 1; j < 10; j++)
    if (bid >= pa.base[j]) mi = j;
  const int K = pa.K[mi], N = pa.N[mi];
  const int rel = bid - pa.base[mi];
  const int ntiles = N >> 5;
  const int bx = rel % ntiles, by = rel / ntiles;
  const float* src = pa.src[mi];
  _Float16* dst = pa.dst[mi];
  const int n0 = bx * 32, k0 = by * 32;
  #pragma unroll
  for (int j = ty; j < 32; j += 8)
    tile[j][tx] = src[(size_t)(k0 + j) * N + n0 + tx];
  __syncthreads();
  #pragma unroll
  for (int j = ty; j < 32; j += 8)
    dst[(size_t)(n0 + j) * K + k0 + tx] = (_Float16)tile[tx][j];
}

// ---------------- V transpose: [b*S+s][h*64+d] -> [(bh*64)+d][s] -----------
__global__ __launch_bounds__(256)
void vt_kernel(const _Float16* __restrict__ src, _Float16* __restrict__ dst,
               int S, int srcStride, int dstStride) {
  __shared__ _Float16 tile[32][33];
  const int tx = threadIdx.x, ty = threadIdx.y;  // (32,8)
  const int s0 = blockIdx.x * 32, d0 = blockIdx.y * 32, bh = blockIdx.z;
  const int b = bh >> 3, h = bh & 7;
  const _Float16* sp = src + (size_t)b * S * srcStride + h * 64 + d0;
  #pragma unroll
  for (int j = ty; j < 32; j += 8) {
    int s = s0 + j; if (s >= S) s = S - 1;
    tile[j][tx] = sp[(size_t)s * srcStride + tx];
  }
  __syncthreads();
  _Float16* dp = dst + ((size_t)bh * 64 + d0) * dstStride + s0;
  #pragma unroll
  for (int j = ty; j < 32; j += 8)
    dp[(size_t)j * dstStride + tx] = tile[tx][j];
}

// ---------------- LayerNorm (row=512), fp32 in -> f16 out ------------------
__global__ __launch_bounds__(256)
void ln_kernel(const float* __restrict__ x, const float* __restrict__ g,
               const float* __restrict__ b, _Float16* __restrict__ out) {
  const int row = blockIdx.x, t = threadIdx.x;
  const float* xr = x + (size_t)row * 512;
  float v0 = xr[t], v1 = xr[t + 256];
  float s1 = v0 + v1, s2 = v0 * v0 + v1 * v1;
  #pragma unroll
  for (int m = 32; m >= 1; m >>= 1) {
    s1 += __shfl_xor(s1, m);
    s2 += __shfl_xor(s2, m);
  }
  __shared__ float red[8];
  if ((t & 63) == 0) { red[t >> 6] = s1; red[4 + (t >> 6)] = s2; }
  __syncthreads();
  s1 = red[0] + red[1] + red[2] + red[3];
  s2 = red[4] + red[5] + red[6] + red[7];
  const float mu = s1 * (1.0f / 512.0f);
  const float var = s2 * (1.0f / 512.0f) - mu * mu;
  const float rs = rsqrtf(var + 1e-5f);
  out[(size_t)row * 512 + t] = (_Float16)((v0 - mu) * rs * g[t] + b[t]);
  out[(size_t)row * 512 + t + 256] =
      (_Float16)((v1 - mu) * rs * g[t + 256] + b[t + 256]);
}

// ---------------- GEMM: C = A[M,K] @ BT[N,K]^T, XCD swizzle ----------------
// PIPE=0: 2-buffer __syncthreads loop. PIPE=1: 3-buffer counted-vmcnt.
// EPI 0: f16 store. EPI 1: Cf = resid + acc + bias. EPI 2: GEGLU dual.
template <int EPI, int GWM, int GWN, int WM, int WN, int MW, int SWZ,
          int PIPE>
__global__ __launch_bounds__(GWM * GWN * 64, MW)
void gemm_bt(const _Float16* __restrict__ A, const _Float16* __restrict__ BT,
             int M, int N, int K, int lda, int ldb, int ldc,
             _Float16* Ch, float* Cf,
             const float* __restrict__ bias, const float* resid) {
  constexpr int NW = GWM * GWN;
  constexpr int BM = GWM * WM * 16;
  constexpr int BN = GWN * WN * 16;
  constexpr int NBUF = PIPE ? 3 : 2;
  // per-thread global_load_lds per stage (uniform across threads)
  constexpr int LPT = (BM / 16) / NW + ((BN / 16) / NW) * ((EPI == 2) ? 2 : 1);
  __shared__ __align__(16) _Float16 As[NBUF][4 * BM * 8];
  __shared__ __align__(16) _Float16 Bs[NBUF][4 * BN * 8];
  __shared__ __align__(16) _Float16 Bs2[(EPI == 2) ? NBUF : 1]
                                      [(EPI == 2) ? 4 * BN * 8 : 8];

  const int t = threadIdx.x;
  const int NNB = (N + BN - 1) / BN;
  int bm, bn;
  if constexpr (SWZ) {
    const int MG = (M / BM) >> 3;
    const int xcd = blockIdx.x & 7;
    const int s = blockIdx.x >> 3;
    bm = xcd * MG + s % MG;
    bn = s / MG;
  } else {
    bn = blockIdx.x % NNB;
    bm = blockIdx.x / NNB;
  }
  const int m0 = bm * BM, n0 = bn * BN;
  const int lane = t & 63, wv = t >> 6;
  const int quad = lane >> 4, l15 = lane & 15;
  const int wm = wv / GWN, wn = wv % GWN;

  f32x4 zero4 = {0.f, 0.f, 0.f, 0.f};
  f32x4 acc[WM][WN];
  f32x4 acc2[(EPI == 2) ? WM : 1][(EPI == 2) ? WN : 1];
  #pragma unroll
  for (int mi = 0; mi < WM; mi++)
    #pragma unroll
    for (int ni = 0; ni < WN; ni++) acc[mi][ni] = zero4;
  if constexpr (EPI == 2) {
    #pragma unroll
    for (int mi = 0; mi < WM; mi++)
      #pragma unroll
      for (int ni = 0; ni < WN; ni++) acc2[mi][ni] = zero4;
  }

  auto stageAll = [&](int k0, int pb) {
    #pragma unroll
    for (int c = wv; c < BM / 16; c += NW) {
      const int s = c * 64 + lane;
      const int q = s / BM;
      const int r = s % BM;
      int rg = m0 + r; if (rg >= M) rg = M - 1;
      gload16(A + (size_t)rg * lda + k0 + q * 8, &As[pb][c * 512]);
    }
    #pragma unroll
    for (int c = wv; c < BN / 16; c += NW) {
      const int s = c * 64 + lane;
      const int q = s / BN;
      const int r = s % BN;
      gload16(BT + (size_t)(n0 + r) * ldb + k0 + q * 8, &Bs[pb][c * 512]);
      if constexpr (EPI == 2)
        gload16(BT + (size_t)(2048 + n0 + r) * ldb + k0 + q * 8,
                &Bs2[pb][c * 512]);
    }
  };

  auto computeTile = [&](int cur) {
    half8 fa[WM], fb[WN], fb2[(EPI == 2) ? WN : 1];
    #pragma unroll
    for (int mi = 0; mi < WM; mi++)
      fa[mi] = *(const half8*)(&As[cur]
          [((size_t)quad * BM + wm * WM * 16 + mi * 16 + l15) * 8]);
    #pragma unroll
    for (int ni = 0; ni < WN; ni++) {
      fb[ni] = *(const half8*)(&Bs[cur]
          [((size_t)quad * BN + wn * WN * 16 + ni * 16 + l15) * 8]);
      if constexpr (EPI == 2)
        fb2[ni] = *(const half8*)(&Bs2[cur]
            [((size_t)quad * BN + wn * WN * 16 + ni * 16 + l15) * 8]);
    }
    if constexpr (PIPE) __builtin_amdgcn_s_setprio(1);
    #pragma unroll
    for (int mi = 0; mi < WM; mi++)
      #pragma unroll
      for (int ni = 0; ni < WN; ni++) {
        acc[mi][ni] = mfma16(fa[mi], fb[ni], acc[mi][ni]);
        if constexpr (EPI == 2)
          acc2[mi][ni] = mfma16(fa[mi], fb2[ni], acc2[mi][ni]);
      }
    if constexpr (PIPE) __builtin_amdgcn_s_setprio(0);
  };

  const int NIT = K >> 5;
  if constexpr (PIPE) {
    // 3-buffer stage-ahead-2, counted vmcnt.
    stageAll(0, 0);
    if (NIT > 1) stageAll(32, 1);
    int cur = 0, pre = 2;
    for (int it = 0; it < NIT; ++it) {
      if (it + 1 < NIT) wait_vmcnt<LPT>();
      else wait_vmcnt<0>();
      __builtin_amdgcn_s_barrier();
      __builtin_amdgcn_sched_barrier(0);
      computeTile(cur);
      asm volatile("s_waitcnt lgkmcnt(0)" ::: "memory");
      __builtin_amdgcn_sched_barrier(0);
      __builtin_amdgcn_s_barrier();
      if (it + 2 < NIT) stageAll((it + 2) << 5, pre);
      cur = (cur == 2) ? 0 : cur + 1;
      pre = (pre == 2) ? 0 : pre + 1;
    }
  } else {
    // 2-buffer __syncthreads loop.
    stageAll(0, 0);
    __syncthreads();
    for (int it = 0; it < NIT; ++it) {
      const int cur = it & 1;
      if (it + 1 < NIT) stageAll((it + 1) << 5, cur ^ 1);
      computeTile(cur);
      __syncthreads();
    }
  }

  #pragma unroll
  for (int mi = 0; mi < WM; mi++) {
    const int rbase = m0 + wm * WM * 16 + mi * 16 + quad * 4;
    #pragma unroll
    for (int r = 0; r < 4; r++) {
      const int row = rbase + r;
      if (row >= M) continue;
      #pragma unroll
      for (int ni = 0; ni < WN; ni++) {
        const int col = n0 + wn * WN * 16 + ni * 16 + l15;
        const float v = acc[mi][ni][r];
        if constexpr (EPI == 0) {
          Ch[(size_t)row * ldc + col] = (_Float16)v;
        } else if constexpr (EPI == 1) {
          Cf[(size_t)row * ldc + col] =
              resid[(size_t)row * ldc + col] + v + bias[col];
        } else {
          const float u = v + bias[col];
          const float gg = acc2[mi][ni][r] + bias[col + 2048];
          const float ge = 0.5f * gg * (1.0f + erff(gg * 0.70710678118f));
          Ch[(size_t)row * ldc + col] = (_Float16)(u * ge);
        }
      }
    }
  }
}

// ---------------- flash attention v2: 8 waves x 16 Q-rows, 3-buffer --------
// 512 threads. Waves 0-3 stage K tile (32sk x 64d), waves 4-7 stage VT tile
// (64d x 32sk); 1 gload16/thread/stage. Grid (Sq/128, B*H) -> 16 waves/CU.
__global__ __launch_bounds__(512)
void attn2(const _Float16* __restrict__ Q, const _Float16* __restrict__ K,
           const _Float16* __restrict__ VT, _Float16* __restrict__ O,
           int qStride, int kStride, long kBatchStride,
           int vtStride, int Sk) {
  __shared__ __align__(16) _Float16 KsL[3][2048];
  __shared__ __align__(16) _Float16 VTsL[3][2048];
  __shared__ __align__(16) _Float16 Ps[8][16][40];

  const int t = threadIdx.x;
  const int w = t >> 6, lane = t & 63, quad = lane >> 4, l15 = lane & 15;
  const int bh = blockIdx.y, b = bh >> 3, h = bh & 7;
  const int q0 = blockIdx.x * 128 + w * 16;

  const _Float16 qscale = (_Float16)(0.125f * 1.44269504f);
  half8 qf[2];
  #pragma unroll
  for (int c = 0; c < 2; c++) {
    const _Float16* qp = Q + (size_t)(b * 1024 + q0 + l15) * qStride +
                         h * 64 + c * 32 + quad * 8;
    half8 v = *(const half8*)qp;
    #pragma unroll
    for (int j = 0; j < 8; j++) v[j] *= qscale;
    qf[c] = v;
  }

  f32x4 zero4 = {0.f, 0.f, 0.f, 0.f};
  f32x4 oa[4];
  float psum[4];
  #pragma unroll
  for (int nt = 0; nt < 4; nt++) oa[nt] = zero4;
  #pragma unroll
  for (int r = 0; r < 4; r++) psum[r] = 0.f;

  const _Float16* kp = K + (size_t)b * kBatchStride + h * 64;
  const _Float16* vtp = VT + (size_t)bh * 64 * vtStride;
  const bool doK = (t < 256);               // wave-uniform
  const int ts = doK ? t : t - 256;
  const int ksk = ts & 31, kc = ts >> 7, kqd = (ts >> 5) & 3;
  const int vd = ts & 63, vqd = ts >> 6;

  auto stageKV = [&](int skb, int pb) {
    if (doK) {
      int skc = skb + ksk; if (skc >= Sk) skc = Sk - 1;
      gload16(kp + (size_t)skc * kStride + kc * 32 + kqd * 8,
              &KsL[pb][ts * 8]);
    } else {
      gload16(vtp + (size_t)vd * vtStride + skb + vqd * 8,
              &VTsL[pb][ts * 8]);
    }
  };

  const int NITa = (Sk + 31) >> 5;
  stageKV(0, 0);
  if (NITa > 1) stageKV(32, 1);

  int cur = 0, pre = 2;
  int it = 0;
  for (int skb = 0; skb < Sk; skb += 32, ++it) {
    if (it + 1 < NITa) wait_vmcnt<1>();
    else wait_vmcnt<0>();
    __builtin_amdgcn_s_barrier();
    __builtin_amdgcn_sched_barrier(0);

    const bool tail = (skb + 32 > Sk);
    #pragma unroll
    for (int ct = 0; ct < 2; ct++) {
      f32x4 s = zero4;
      half8 kb0 = *(const half8*)(&KsL[cur][(quad * 32 + ct * 16 + l15) * 8]);
      half8 kb1 =
          *(const half8*)(&KsL[cur][(128 + quad * 32 + ct * 16 + l15) * 8]);
      s = mfma16(qf[0], kb0, s);
      s = mfma16(qf[1], kb1, s);
      if (tail) {
        const bool valid = (skb + ct * 16 + l15) < Sk;
        #pragma unroll
        for (int r = 0; r < 4; r++)
          if (!valid) s[r] = -__builtin_inff();
      }
      #pragma unroll
      for (int r = 0; r < 4; r++) {
        const float e = exp2f(s[r]);
        psum[r] += e;
        Ps[w][quad * 4 + r][ct * 16 + l15] = (_Float16)e;
      }
    }
    {
      const half8 pf = *(const half8*)(&Ps[w][l15][quad * 8]);
      #pragma unroll
      for (int nt = 0; nt < 4; nt++) {
        const half8 vf =
            *(const half8*)(&VTsL[cur][(quad * 64 + nt * 16 + l15) * 8]);
        oa[nt] = mfma16(pf, vf, oa[nt]);
      }
    }

    asm volatile("s_waitcnt lgkmcnt(0)" ::: "memory");
    __builtin_amdgcn_sched_barrier(0);
    __builtin_amdgcn_s_barrier();
    if (it + 2 < NITa) stageKV(skb + 64, pre);
    cur = (cur == 2) ? 0 : cur + 1;
    pre = (pre == 2) ? 0 : pre + 1;
  }

  #pragma unroll
  for (int r = 0; r < 4; r++) {
    #pragma unroll
    for (int mm = 1; mm < 16; mm <<= 1)
      psum[r] += __shfl_xor(psum[r], mm);
    psum[r] = 1.0f / psum[r];
  }

  #pragma unroll
  for (int nt = 0; nt < 4; nt++)
    #pragma unroll
    for (int r = 0; r < 4; r++) {
      const size_t row = (size_t)(b * 1024 + q0 + quad * 4 + r);
      O[row * 512 + h * 64 + nt * 16 + l15] =
          (_Float16)(oa[nt][r] * psum[r]);
    }
}

// ---------------------------------------------------------------------------
extern "C" void kernel_launch(void* const* d_in, const int* in_sizes, int n_in,
                              void* d_out, int out_size, void* d_ws,
                              size_t ws_size, hipStream_t stream) {
  const float* x    = (const float*)d_in[0];
  const float* enc  = (const float*)d_in[1];
  const float* ln1g = (const float*)d_in[2];
  const float* ln1b = (const float*)d_in[3];
  const float* wq1  = (const float*)d_in[4];
  const float* wk1  = (const float*)d_in[5];
  const float* wv1  = (const float*)d_in[6];
  const float* wo1  = (const float*)d_in[7];
  const float* bo1  = (const float*)d_in[8];
  const float* ln2g = (const float*)d_in[9];
  const float* ln2b = (const float*)d_in[10];
  const float* wq2  = (const float*)d_in[11];
  const float* wk2  = (const float*)d_in[12];
  const float* wv2  = (const float*)d_in[13];
  const float* wo2  = (const float*)d_in[14];
  const float* bo2  = (const float*)d_in[15];
  const float* ln3g = (const float*)d_in[16];
  const float* ln3b = (const float*)d_in[17];
  const float* wg   = (const float*)d_in[18];
  const float* bg   = (const float*)d_in[19];
  const float* wf   = (const float*)d_in[20];
  const float* bfp  = (const float*)d_in[21];
  float* out = (float*)d_out;

  char* ws = (char*)d_ws;
  _Float16* qkvT  = (_Float16*)(ws + 0);         // [1536,512]
  _Float16* q2T   = (_Float16*)(ws + 1572864);   // [512,512]
  _Float16* kv2T  = (_Float16*)(ws + 2097152);   // [1024,768]
  _Float16* wo1T  = (_Float16*)(ws + 3670016);   // [512,512]
  _Float16* wo2T  = (_Float16*)(ws + 4194304);   // [512,512]
  _Float16* wgT   = (_Float16*)(ws + 4718592);   // [4096,512]
  _Float16* wfT   = (_Float16*)(ws + 8912896);   // [512,2048]
  _Float16* hbuf  = (_Float16*)(ws + 11010048);  // [8192,512] (VTself in attn1)
  _Float16* qkv   = (_Float16*)(ws + 19398656);  // [8192,1536]
  _Float16* q2b   = (_Float16*)(ws + 44564480);  // [8192,512]
  _Float16* kv2b  = (_Float16*)(ws + 52953088);  // [616,1024]
  _Float16* attnb = (_Float16*)(ws + 54214656);  // [8192,512]
  _Float16* ench  = (_Float16*)(ws + 62603264);  // [616,768]
  _Float16* ffb   = (_Float16*)(ws + 19398656);  // [8192,2048] aliases qkv+q2b
  _Float16* VTself = hbuf;                       // [4096,1024]
  _Float16* VTc   = (_Float16*)(ws + 62603264);  // [4096,96] over ench (dead
                                                 // after kv2 GEMM)

  // ---- fused prep: weights + enc + LN1 (one launch) ----
  PrepArgs pa;
  const float* srcs[10] = {wq1, wk1, wv1, wo1, wq2, wk2, wv2, wo2, wg, wf};
  _Float16* dsts[10] = {qkvT, qkvT + 512 * 512, qkvT + 1024 * 512, wo1T, q2T,
                        kv2T, kv2T + 512 * 768, wo2T, wgT, wfT};
  const int Ks[10] = {512, 512, 512, 512, 512, 768, 768, 512, 512, 2048};
  const int Ns[10] = {512, 512, 512, 512, 512, 512, 512, 512, 4096, 512};
  int base = 0;
  for (int i = 0; i < 10; i++) {
    pa.src[i] = srcs[i]; pa.dst[i] = dsts[i];
    pa.K[i] = Ks[i]; pa.N[i] = Ns[i]; pa.base[i] = base;
    base += (Ks[i] >> 5) * (Ns[i] >> 5);
  }
  pa.enc = enc; pa.ench = ench; pa.encBase = base; pa.nEnc = 473088;
  base += (473088 + 255) / 256;
  pa.x = x; pa.ln1g = ln1g; pa.ln1b = ln1b; pa.hbuf = hbuf; pa.lnBase = base;
  base += 8192;
  prep_all<<<base, dim3(32, 8), 0, stream>>>(pa);

  const dim3 tb(32, 8);

  // ---- self-attention block ----
  gemm_bt<0, 2, 2, 4, 4, 3, 1, 1><<<768, 256, 0, stream>>>(
      hbuf, qkvT, 8192, 1536, 512, 512, 512, 1536,
      qkv, nullptr, nullptr, nullptr);
  vt_kernel<<<dim3(32, 2, 64), tb, 0, stream>>>(qkv + 1024, VTself, 1024,
                                                1536, 1024);
  attn2<<<dim3(8, 64), 512, 0, stream>>>(qkv, qkv + 512, VTself, attnb,
                                         1536, 1536, (long)1024 * 1536,
                                         1024, 1024);
  gemm_bt<1, 1, 4, 4, 2, 4, 1, 1><<<512, 256, 0, stream>>>(
      attnb, wo1T, 8192, 512, 512, 512, 512, 512, nullptr, out, bo1, x);

  // ---- cross-attention block ----
  ln_kernel<<<8192, 256, 0, stream>>>(out, ln2g, ln2b, hbuf);
  gemm_bt<0, 1, 4, 4, 2, 4, 1, 1><<<512, 256, 0, stream>>>(
      hbuf, q2T, 8192, 512, 512, 512, 512, 512,
      q2b, nullptr, nullptr, nullptr);
  gemm_bt<0, 1, 4, 4, 2, 4, 0, 1><<<80, 256, 0, stream>>>(
      ench, kv2T, 616, 1024, 768, 768, 768, 1024,
      kv2b, nullptr, nullptr, nullptr);
  vt_kernel<<<dim3(3, 2, 64), tb, 0, stream>>>(kv2b + 512, VTc, 77, 1024, 96);
  attn2<<<dim3(8, 64), 512, 0, stream>>>(q2b, kv2b, VTc, attnb,
                                         512, 1024, (long)77 * 1024, 96, 77);
  gemm_bt<1, 1, 4, 4, 2, 4, 1, 1><<<512, 256, 0, stream>>>(
      attnb, wo2T, 8192, 512, 512, 512, 512, 512, nullptr, out, bo2, out);

  // ---- GEGLU feed-forward ----
  ln_kernel<<<8192, 256, 0, stream>>>(out, ln3g, ln3b, hbuf);
  // GEGLU: 128x128-dual, 8 waves, 2 blocks/CU (R14, 85.0us)
  gemm_bt<2, 2, 4, 4, 2, 4, 1, 0><<<1024, 512, 0, stream>>>(
      hbuf, wgT, 8192, 2048, 512, 512, 512, 2048,
      ffb, nullptr, bg, nullptr);
  gemm_bt<1, 1, 4, 4, 2, 4, 1, 1><<<512, 256, 0, stream>>>(
      ffb, wfT, 8192, 512, 2048, 2048, 2048, 512,
      nullptr, out, bfp, out);
}

// Round 7
// 430.857 us; speedup vs baseline: 1.0653x; 1.0294x over previous
//
#include <hip/hip_runtime.h>

// ---------------------------------------------------------------------------
// BasicTransformerBlock on MI355X (gfx950).
// R16: propagate R15's confirmed lever (same tile, 2x waves/block) to all
// remaining GEMMs. R15: attn 4w->8w at fixed tile/grid gave -15.5us total,
// matching prediction; lever now validated. QKV: 128x128 tile, 4->8 waves
// (GWM2 GWN4 WM4 WN2, 512thr, grid 768; reg-total ~82 -> 6 waves/SIMD -> up
// to 24 waves/CU, was 12). wo1/q2/wo2/wf: 64x128 tile, 4->8 waves
// (GWM2 GWN4 WM2 WN2, 512thr, grid 512 -> 16 waves/CU, was 8). Per-wave acc
// halves (AGPR 32/16) so register residency improves. PIPE=0 for the new
// configs (schedule axis null per R9/R10/R13). GEGLU frozen at R14 (85-87us),
// attn frozen at R15.
// ---------------------------------------------------------------------------

typedef _Float16 half8 __attribute__((ext_vector_type(8)));
typedef float f32x4 __attribute__((ext_vector_type(4)));

__device__ __forceinline__ f32x4 mfma16(half8 a, half8 b, f32x4 c) {
  return __builtin_amdgcn_mfma_f32_16x16x32_f16(a, b, c, 0, 0, 0);
}

__device__ __forceinline__ void gload16(const _Float16* g, _Float16* l) {
  __builtin_amdgcn_global_load_lds(
      (const __attribute__((address_space(1))) void*)g,
      (__attribute__((address_space(3))) void*)l, 16, 0, 0);
}

template <int N>
__device__ __forceinline__ void wait_vmcnt() {
  if constexpr (N == 0)
    asm volatile("s_waitcnt vmcnt(0)" ::: "memory");
  else if constexpr (N == 1)
    asm volatile("s_waitcnt vmcnt(1)" ::: "memory");
  else if constexpr (N == 2)
    asm volatile("s_waitcnt vmcnt(2)" ::: "memory");
  else if constexpr (N == 3)
    asm volatile("s_waitcnt vmcnt(3)" ::: "memory");
  else if constexpr (N == 4)
    asm volatile("s_waitcnt vmcnt(4)" ::: "memory");
  else
    static_assert(N <= 4, "add a case");
}

// ---------------- fused prep: 10 weight transposes + enc cvt + LN1 ---------
struct PrepArgs {
  const float* src[10];
  _Float16* dst[10];
  int K[10], N[10], base[10];
  const float* enc;
  _Float16* ench;
  int encBase, nEnc;
  const float* x;
  const float* ln1g;
  const float* ln1b;
  _Float16* hbuf;
  int lnBase;  // first block index of LN rows (8192 rows follow)
};

__global__ __launch_bounds__(256)
void prep_all(PrepArgs pa) {
  __shared__ float tile[32][33];
  const int bid = blockIdx.x;
  const int tx = threadIdx.x, ty = threadIdx.y;
  const int t = ty * 32 + tx;
  if (bid >= pa.lnBase) {
    // -------- LayerNorm1 row --------
    const int row = bid - pa.lnBase;
    const float* xr = pa.x + (size_t)row * 512;
    float v0 = xr[t], v1 = xr[t + 256];
    float s1 = v0 + v1, s2 = v0 * v0 + v1 * v1;
    #pragma unroll
    for (int m = 32; m >= 1; m >>= 1) {
      s1 += __shfl_xor(s1, m);
      s2 += __shfl_xor(s2, m);
    }
    __shared__ float red[8];
    if ((t & 63) == 0) { red[t >> 6] = s1; red[4 + (t >> 6)] = s2; }
    __syncthreads();
    s1 = red[0] + red[1] + red[2] + red[3];
    s2 = red[4] + red[5] + red[6] + red[7];
    const float mu = s1 * (1.0f / 512.0f);
    const float var = s2 * (1.0f / 512.0f) - mu * mu;
    const float rs = rsqrtf(var + 1e-5f);
    pa.hbuf[(size_t)row * 512 + t] =
        (_Float16)((v0 - mu) * rs * pa.ln1g[t] + pa.ln1b[t]);
    pa.hbuf[(size_t)row * 512 + t + 256] =
        (_Float16)((v1 - mu) * rs * pa.ln1g[t + 256] + pa.ln1b[t + 256]);
    return;
  }
  if (bid >= pa.encBase) {
    const int i = (bid - pa.encBase) * 256 + t;
    if (i < pa.nEnc) pa.ench[i] = (_Float16)pa.enc[i];
    return;
  }
  int mi = 0;
  #pragma unroll
  for (int j = 1; j < 10; j++)
    if (bid >= pa.base[j]) mi = j;
  const int K = pa.K[mi], N = pa.N[mi];
  const int rel = bid - pa.base[mi];
  const int ntiles = N >> 5;
  const int bx = rel % ntiles, by = rel / ntiles;
  const float* src = pa.src[mi];
  _Float16* dst = pa.dst[mi];
  const int n0 = bx * 32, k0 = by * 32;
  #pragma unroll
  for (int j = ty; j < 32; j += 8)
    tile[j][tx] = src[(size_t)(k0 + j) * N + n0 + tx];
  __syncthreads();
  #pragma unroll
  for (int j = ty; j < 32; j += 8)
    dst[(size_t)(n0 + j) * K + k0 + tx] = (_Float16)tile[tx][j];
}

// ---------------- V transpose: [b*S+s][h*64+d] -> [(bh*64)+d][s] -----------
__global__ __launch_bounds__(256)
void vt_kernel(const _Float16* __restrict__ src, _Float16* __restrict__ dst,
               int S, int srcStride, int dstStride) {
  __shared__ _Float16 tile[32][33];
  const int tx = threadIdx.x, ty = threadIdx.y;  // (32,8)
  const int s0 = blockIdx.x * 32, d0 = blockIdx.y * 32, bh = blockIdx.z;
  const int b = bh >> 3, h = bh & 7;
  const _Float16* sp = src + (size_t)b * S * srcStride + h * 64 + d0;
  #pragma unroll
  for (int j = ty; j < 32; j += 8) {
    int s = s0 + j; if (s >= S) s = S - 1;
    tile[j][tx] = sp[(size_t)s * srcStride + tx];
  }
  __syncthreads();
  _Float16* dp = dst + ((size_t)bh * 64 + d0) * dstStride + s0;
  #pragma unroll
  for (int j = ty; j < 32; j += 8)
    dp[(size_t)j * dstStride + tx] = tile[tx][j];
}

// ---------------- LayerNorm (row=512), fp32 in -> f16 out ------------------
__global__ __launch_bounds__(256)
void ln_kernel(const float* __restrict__ x, const float* __restrict__ g,
               const float* __restrict__ b, _Float16* __restrict__ out) {
  const int row = blockIdx.x, t = threadIdx.x;
  const float* xr = x + (size_t)row * 512;
  float v0 = xr[t], v1 = xr[t + 256];
  float s1 = v0 + v1, s2 = v0 * v0 + v1 * v1;
  #pragma unroll
  for (int m = 32; m >= 1; m >>= 1) {
    s1 += __shfl_xor(s1, m);
    s2 += __shfl_xor(s2, m);
  }
  __shared__ float red[8];
  if ((t & 63) == 0) { red[t >> 6] = s1; red[4 + (t >> 6)] = s2; }
  __syncthreads();
  s1 = red[0] + red[1] + red[2] + red[3];
  s2 = red[4] + red[5] + red[6] + red[7];
  const float mu = s1 * (1.0f / 512.0f);
  const float var = s2 * (1.0f / 512.0f) - mu * mu;
  const float rs = rsqrtf(var + 1e-5f);
  out[(size_t)row * 512 + t] = (_Float16)((v0 - mu) * rs * g[t] + b[t]);
  out[(size_t)row * 512 + t + 256] =
      (_Float16)((v1 - mu) * rs * g[t + 256] + b[t + 256]);
}

// ---------------- GEMM: C = A[M,K] @ BT[N,K]^T, XCD swizzle ----------------
// PIPE=0: 2-buffer __syncthreads loop. PIPE=1: 3-buffer counted-vmcnt.
// EPI 0: f16 store. EPI 1: Cf = resid + acc + bias. EPI 2: GEGLU dual.
template <int EPI, int GWM, int GWN, int WM, int WN, int MW, int SWZ,
          int PIPE>
__global__ __launch_bounds__(GWM * GWN * 64, MW)
void gemm_bt(const _Float16* __restrict__ A, const _Float16* __restrict__ BT,
             int M, int N, int K, int lda, int ldb, int ldc,
             _Float16* Ch, float* Cf,
             const float* __restrict__ bias, const float* resid) {
  constexpr int NW = GWM * GWN;
  constexpr int BM = GWM * WM * 16;
  constexpr int BN = GWN * WN * 16;
  constexpr int NBUF = PIPE ? 3 : 2;
  // per-thread global_load_lds per stage (uniform across threads)
  constexpr int LPT = (BM / 16) / NW + ((BN / 16) / NW) * ((EPI == 2) ? 2 : 1);
  __shared__ __align__(16) _Float16 As[NBUF][4 * BM * 8];
  __shared__ __align__(16) _Float16 Bs[NBUF][4 * BN * 8];
  __shared__ __align__(16) _Float16 Bs2[(EPI == 2) ? NBUF : 1]
                                      [(EPI == 2) ? 4 * BN * 8 : 8];

  const int t = threadIdx.x;
  const int NNB = (N + BN - 1) / BN;
  int bm, bn;
  if constexpr (SWZ) {
    const int MG = (M / BM) >> 3;
    const int xcd = blockIdx.x & 7;
    const int s = blockIdx.x >> 3;
    bm = xcd * MG + s % MG;
    bn = s / MG;
  } else {
    bn = blockIdx.x % NNB;
    bm = blockIdx.x / NNB;
  }
  const int m0 = bm * BM, n0 = bn * BN;
  const int lane = t & 63, wv = t >> 6;
  const int quad = lane >> 4, l15 = lane & 15;
  const int wm = wv / GWN, wn = wv % GWN;

  f32x4 zero4 = {0.f, 0.f, 0.f, 0.f};
  f32x4 acc[WM][WN];
  f32x4 acc2[(EPI == 2) ? WM : 1][(EPI == 2) ? WN : 1];
  #pragma unroll
  for (int mi = 0; mi < WM; mi++)
    #pragma unroll
    for (int ni = 0; ni < WN; ni++) acc[mi][ni] = zero4;
  if constexpr (EPI == 2) {
    #pragma unroll
    for (int mi = 0; mi < WM; mi++)
      #pragma unroll
      for (int ni = 0; ni < WN; ni++) acc2[mi][ni] = zero4;
  }

  auto stageAll = [&](int k0, int pb) {
    #pragma unroll
    for (int c = wv; c < BM / 16; c += NW) {
      const int s = c * 64 + lane;
      const int q = s / BM;
      const int r = s % BM;
      int rg = m0 + r; if (rg >= M) rg = M - 1;
      gload16(A + (size_t)rg * lda + k0 + q * 8, &As[pb][c * 512]);
    }
    #pragma unroll
    for (int c = wv; c < BN / 16; c += NW) {
      const int s = c * 64 + lane;
      const int q = s / BN;
      const int r = s % BN;
      gload16(BT + (size_t)(n0 + r) * ldb + k0 + q * 8, &Bs[pb][c * 512]);
      if constexpr (EPI == 2)
        gload16(BT + (size_t)(2048 + n0 + r) * ldb + k0 + q * 8,
                &Bs2[pb][c * 512]);
    }
  };

  auto computeTile = [&](int cur) {
    half8 fa[WM], fb[WN], fb2[(EPI == 2) ? WN : 1];
    #pragma unroll
    for (int mi = 0; mi < WM; mi++)
      fa[mi] = *(const half8*)(&As[cur]
          [((size_t)quad * BM + wm * WM * 16 + mi * 16 + l15) * 8]);
    #pragma unroll
    for (int ni = 0; ni < WN; ni++) {
      fb[ni] = *(const half8*)(&Bs[cur]
          [((size_t)quad * BN + wn * WN * 16 + ni * 16 + l15) * 8]);
      if constexpr (EPI == 2)
        fb2[ni] = *(const half8*)(&Bs2[cur]
            [((size_t)quad * BN + wn * WN * 16 + ni * 16 + l15) * 8]);
    }
    if constexpr (PIPE) __builtin_amdgcn_s_setprio(1);
    #pragma unroll
    for (int mi = 0; mi < WM; mi++)
      #pragma unroll
      for (int ni = 0; ni < WN; ni++) {
        acc[mi][ni] = mfma16(fa[mi], fb[ni], acc[mi][ni]);
        if constexpr (EPI == 2)
          acc2[mi][ni] = mfma16(fa[mi], fb2[ni], acc2[mi][ni]);
      }
    if constexpr (PIPE) __builtin_amdgcn_s_setprio(0);
  };

  const int NIT = K >> 5;
  if constexpr (PIPE) {
    // 3-buffer stage-ahead-2, counted vmcnt.
    stageAll(0, 0);
    if (NIT > 1) stageAll(32, 1);
    int cur = 0, pre = 2;
    for (int it = 0; it < NIT; ++it) {
      if (it + 1 < NIT) wait_vmcnt<LPT>();
      else wait_vmcnt<0>();
      __builtin_amdgcn_s_barrier();
      __builtin_amdgcn_sched_barrier(0);
      computeTile(cur);
      asm volatile("s_waitcnt lgkmcnt(0)" ::: "memory");
      __builtin_amdgcn_sched_barrier(0);
      __builtin_amdgcn_s_barrier();
      if (it + 2 < NIT) stageAll((it + 2) << 5, pre);
      cur = (cur == 2) ? 0 : cur + 1;
      pre = (pre == 2) ? 0 : pre + 1;
    }
  } else {
    // 2-buffer __syncthreads loop.
    stageAll(0, 0);
    __syncthreads();
    for (int it = 0; it < NIT; ++it) {
      const int cur = it & 1;
      if (it + 1 < NIT) stageAll((it + 1) << 5, cur ^ 1);
      computeTile(cur);
      __syncthreads();
    }
  }

  #pragma unroll
  for (int mi = 0; mi < WM; mi++) {
    const int rbase = m0 + wm * WM * 16 + mi * 16 + quad * 4;
    #pragma unroll
    for (int r = 0; r < 4; r++) {
      const int row = rbase + r;
      if (row >= M) continue;
      #pragma unroll
      for (int ni = 0; ni < WN; ni++) {
        const int col = n0 + wn * WN * 16 + ni * 16 + l15;
        const float v = acc[mi][ni][r];
        if constexpr (EPI == 0) {
          Ch[(size_t)row * ldc + col] = (_Float16)v;
        } else if constexpr (EPI == 1) {
          Cf[(size_t)row * ldc + col] =
              resid[(size_t)row * ldc + col] + v + bias[col];
        } else {
          const float u = v + bias[col];
          const float gg = acc2[mi][ni][r] + bias[col + 2048];
          const float ge = 0.5f * gg * (1.0f + erff(gg * 0.70710678118f));
          Ch[(size_t)row * ldc + col] = (_Float16)(u * ge);
        }
      }
    }
  }
}

// ---------------- flash attention v2: 8 waves x 16 Q-rows, 3-buffer --------
// 512 threads. Waves 0-3 stage K tile (32sk x 64d), waves 4-7 stage VT tile
// (64d x 32sk); 1 gload16/thread/stage. Grid (Sq/128, B*H) -> 16 waves/CU.
__global__ __launch_bounds__(512)
void attn2(const _Float16* __restrict__ Q, const _Float16* __restrict__ K,
           const _Float16* __restrict__ VT, _Float16* __restrict__ O,
           int qStride, int kStride, long kBatchStride,
           int vtStride, int Sk) {
  __shared__ __align__(16) _Float16 KsL[3][2048];
  __shared__ __align__(16) _Float16 VTsL[3][2048];
  __shared__ __align__(16) _Float16 Ps[8][16][40];

  const int t = threadIdx.x;
  const int w = t >> 6, lane = t & 63, quad = lane >> 4, l15 = lane & 15;
  const int bh = blockIdx.y, b = bh >> 3, h = bh & 7;
  const int q0 = blockIdx.x * 128 + w * 16;

  const _Float16 qscale = (_Float16)(0.125f * 1.44269504f);
  half8 qf[2];
  #pragma unroll
  for (int c = 0; c < 2; c++) {
    const _Float16* qp = Q + (size_t)(b * 1024 + q0 + l15) * qStride +
                         h * 64 + c * 32 + quad * 8;
    half8 v = *(const half8*)qp;
    #pragma unroll
    for (int j = 0; j < 8; j++) v[j] *= qscale;
    qf[c] = v;
  }

  f32x4 zero4 = {0.f, 0.f, 0.f, 0.f};
  f32x4 oa[4];
  float psum[4];
  #pragma unroll
  for (int nt = 0; nt < 4; nt++) oa[nt] = zero4;
  #pragma unroll
  for (int r = 0; r < 4; r++) psum[r] = 0.f;

  const _Float16* kp = K + (size_t)b * kBatchStride + h * 64;
  const _Float16* vtp = VT + (size_t)bh * 64 * vtStride;
  const bool doK = (t < 256);               // wave-uniform
  const int ts = doK ? t : t - 256;
  const int ksk = ts & 31, kc = ts >> 7, kqd = (ts >> 5) & 3;
  const int vd = ts & 63, vqd = ts >> 6;

  auto stageKV = [&](int skb, int pb) {
    if (doK) {
      int skc = skb + ksk; if (skc >= Sk) skc = Sk - 1;
      gload16(kp + (size_t)skc * kStride + kc * 32 + kqd * 8,
              &KsL[pb][ts * 8]);
    } else {
      gload16(vtp + (size_t)vd * vtStride + skb + vqd * 8,
              &VTsL[pb][ts * 8]);
    }
  };

  const int NITa = (Sk + 31) >> 5;
  stageKV(0, 0);
  if (NITa > 1) stageKV(32, 1);

  int cur = 0, pre = 2;
  int it = 0;
  for (int skb = 0; skb < Sk; skb += 32, ++it) {
    if (it + 1 < NITa) wait_vmcnt<1>();
    else wait_vmcnt<0>();
    __builtin_amdgcn_s_barrier();
    __builtin_amdgcn_sched_barrier(0);

    const bool tail = (skb + 32 > Sk);
    #pragma unroll
    for (int ct = 0; ct < 2; ct++) {
      f32x4 s = zero4;
      half8 kb0 = *(const half8*)(&KsL[cur][(quad * 32 + ct * 16 + l15) * 8]);
      half8 kb1 =
          *(const half8*)(&KsL[cur][(128 + quad * 32 + ct * 16 + l15) * 8]);
      s = mfma16(qf[0], kb0, s);
      s = mfma16(qf[1], kb1, s);
      if (tail) {
        const bool valid = (skb + ct * 16 + l15) < Sk;
        #pragma unroll
        for (int r = 0; r < 4; r++)
          if (!valid) s[r] = -__builtin_inff();
      }
      #pragma unroll
      for (int r = 0; r < 4; r++) {
        const float e = exp2f(s[r]);
        psum[r] += e;
        Ps[w][quad * 4 + r][ct * 16 + l15] = (_Float16)e;
      }
    }
    {
      const half8 pf = *(const half8*)(&Ps[w][l15][quad * 8]);
      #pragma unroll
      for (int nt = 0; nt < 4; nt++) {
        const half8 vf =
            *(const half8*)(&VTsL[cur][(quad * 64 + nt * 16 + l15) * 8]);
        oa[nt] = mfma16(pf, vf, oa[nt]);
      }
    }

    asm volatile("s_waitcnt lgkmcnt(0)" ::: "memory");
    __builtin_amdgcn_sched_barrier(0);
    __builtin_amdgcn_s_barrier();
    if (it + 2 < NITa) stageKV(skb + 64, pre);
    cur = (cur == 2) ? 0 : cur + 1;
    pre = (pre == 2) ? 0 : pre + 1;
  }

  #pragma unroll
  for (int r = 0; r < 4; r++) {
    #pragma unroll
    for (int mm = 1; mm < 16; mm <<= 1)
      psum[r] += __shfl_xor(psum[r], mm);
    psum[r] = 1.0f / psum[r];
  }

  #pragma unroll
  for (int nt = 0; nt < 4; nt++)
    #pragma unroll
    for (int r = 0; r < 4; r++) {
      const size_t row = (size_t)(b * 1024 + q0 + quad * 4 + r);
      O[row * 512 + h * 64 + nt * 16 + l15] =
          (_Float16)(oa[nt][r] * psum[r]);
    }
}

// ---------------------------------------------------------------------------
extern "C" void kernel_launch(void* const* d_in, const int* in_sizes, int n_in,
                              void* d_out, int out_size, void* d_ws,
                              size_t ws_size, hipStream_t stream) {
  const float* x    = (const float*)d_in[0];
  const float* enc  = (const float*)d_in[1];
  const float* ln1g = (const float*)d_in[2];
  const float* ln1b = (const float*)d_in[3];
  const float* wq1  = (const float*)d_in[4];
  const float* wk1  = (const float*)d_in[5];
  const float* wv1  = (const float*)d_in[6];
  const float* wo1  = (const float*)d_in[7];
  const float* bo1  = (const float*)d_in[8];
  const float* ln2g = (const float*)d_in[9];
  const float* ln2b = (const float*)d_in[10];
  const float* wq2  = (const float*)d_in[11];
  const float* wk2  = (const float*)d_in[12];
  const float* wv2  = (const float*)d_in[13];
  const float* wo2  = (const float*)d_in[14];
  const float* bo2  = (const float*)d_in[15];
  const float* ln3g = (const float*)d_in[16];
  const float* ln3b = (const float*)d_in[17];
  const float* wg   = (const float*)d_in[18];
  const float* bg   = (const float*)d_in[19];
  const float* wf   = (const float*)d_in[20];
  const float* bfp  = (const float*)d_in[21];
  float* out = (float*)d_out;

  char* ws = (char*)d_ws;
  _Float16* qkvT  = (_Float16*)(ws + 0);         // [1536,512]
  _Float16* q2T   = (_Float16*)(ws + 1572864);   // [512,512]
  _Float16* kv2T  = (_Float16*)(ws + 2097152);   // [1024,768]
  _Float16* wo1T  = (_Float16*)(ws + 3670016);   // [512,512]
  _Float16* wo2T  = (_Float16*)(ws + 4194304);   // [512,512]
  _Float16* wgT   = (_Float16*)(ws + 4718592);   // [4096,512]
  _Float16* wfT   = (_Float16*)(ws + 8912896);   // [512,2048]
  _Float16* hbuf  = (_Float16*)(ws + 11010048);  // [8192,512] (VTself in attn1)
  _Float16* qkv   = (_Float16*)(ws + 19398656);  // [8192,1536]
  _Float16* q2b   = (_Float16*)(ws + 44564480);  // [8192,512]
  _Float16* kv2b  = (_Float16*)(ws + 52953088);  // [616,1024]
  _Float16* attnb = (_Float16*)(ws + 54214656);  // [8192,512]
  _Float16* ench  = (_Float16*)(ws + 62603264);  // [616,768]
  _Float16* ffb   = (_Float16*)(ws + 19398656);  // [8192,2048] aliases qkv+q2b
  _Float16* VTself = hbuf;                       // [4096,1024]
  _Float16* VTc   = (_Float16*)(ws + 62603264);  // [4096,96] over ench (dead
                                                 // after kv2 GEMM)

  // ---- fused prep: weights + enc + LN1 (one launch) ----
  PrepArgs pa;
  const float* srcs[10] = {wq1, wk1, wv1, wo1, wq2, wk2, wv2, wo2, wg, wf};
  _Float16* dsts[10] = {qkvT, qkvT + 512 * 512, qkvT + 1024 * 512, wo1T, q2T,
                        kv2T, kv2T + 512 * 768, wo2T, wgT, wfT};
  const int Ks[10] = {512, 512, 512, 512, 512, 768, 768, 512, 512, 2048};
  const int Ns[10] = {512, 512, 512, 512, 512, 512, 512, 512, 4096, 512};
  int base = 0;
  for (int i = 0; i < 10; i++) {
    pa.src[i] = srcs[i]; pa.dst[i] = dsts[i];
    pa.K[i] = Ks[i]; pa.N[i] = Ns[i]; pa.base[i] = base;
    base += (Ks[i] >> 5) * (Ns[i] >> 5);
  }
  pa.enc = enc; pa.ench = ench; pa.encBase = base; pa.nEnc = 473088;
  base += (473088 + 255) / 256;
  pa.x = x; pa.ln1g = ln1g; pa.ln1b = ln1b; pa.hbuf = hbuf; pa.lnBase = base;
  base += 8192;
  prep_all<<<base, dim3(32, 8), 0, stream>>>(pa);

  const dim3 tb(32, 8);

  // ---- self-attention block ----
  // QKV: 128x128 tile, 8 waves (was 4), grid 768 -> up to 24 waves/CU
  gemm_bt<0, 2, 4, 4, 2, 4, 1, 0><<<768, 512, 0, stream>>>(
      hbuf, qkvT, 8192, 1536, 512, 512, 512, 1536,
      qkv, nullptr, nullptr, nullptr);
  vt_kernel<<<dim3(32, 2, 64), tb, 0, stream>>>(qkv + 1024, VTself, 1024,
                                                1536, 1024);
  attn2<<<dim3(8, 64), 512, 0, stream>>>(qkv, qkv + 512, VTself, attnb,
                                         1536, 1536, (long)1024 * 1536,
                                         1024, 1024);
  // wo1: 64x128 tile, 8 waves (was 4), grid 512 -> 16 waves/CU
  gemm_bt<1, 2, 4, 2, 2, 4, 1, 0><<<512, 512, 0, stream>>>(
      attnb, wo1T, 8192, 512, 512, 512, 512, 512, nullptr, out, bo1, x);

  // ---- cross-attention block ----
  ln_kernel<<<8192, 256, 0, stream>>>(out, ln2g, ln2b, hbuf);
  gemm_bt<0, 2, 4, 2, 2, 4, 1, 0><<<512, 512, 0, stream>>>(
      hbuf, q2T, 8192, 512, 512, 512, 512, 512,
      q2b, nullptr, nullptr, nullptr);
  gemm_bt<0, 1, 4, 4, 2, 4, 0, 1><<<80, 256, 0, stream>>>(
      ench, kv2T, 616, 1024, 768, 768, 768, 1024,
      kv2b, nullptr, nullptr, nullptr);
  vt_kernel<<<dim3(3, 2, 64), tb, 0, stream>>>(kv2b + 512, VTc, 77, 1024, 96);
  attn2<<<dim3(8, 64), 512, 0, stream>>>(q2b, kv2b, VTc, attnb,
                                         512, 1024, (long)77 * 1024, 96, 77);
  gemm_bt<1, 2, 4, 2, 2, 4, 1, 0><<<512, 512, 0, stream>>>(
      attnb, wo2T, 8192, 512, 512, 512, 512, 512, nullptr, out, bo2, out);

  // ---- GEGLU feed-forward ----
  ln_kernel<<<8192, 256, 0, stream>>>(out, ln3g, ln3b, hbuf);
  // GEGLU: 128x128-dual, 8 waves (R14, 85-87us)
  gemm_bt<2, 2, 4, 4, 2, 4, 1, 0><<<1024, 512, 0, stream>>>(
      hbuf, wgT, 8192, 2048, 512, 512, 512, 2048,
      ffb, nullptr, bg, nullptr);
  // wf: 64x128 tile, 8 waves (was 4), grid 512 -> 16 waves/CU
  gemm_bt<1, 2, 4, 2, 2, 4, 1, 0><<<512, 512, 0, stream>>>(
      ffb, wfT, 8192, 512, 2048, 2048, 2048, 512,
      nullptr, out, bfp, out);
}

// Round 8
// 424.082 us; speedup vs baseline: 1.0823x; 1.0160x over previous
//
#include <hip/hip_runtime.h>

// ---------------------------------------------------------------------------
// BasicTransformerBlock on MI355X (gfx950).
// R17: third application of the validated lever (same tile, 2x waves/block).
// R15 attn 8->16 waves/CU: -15.5us. R16 GEMMs: -12.6us. Now wo-family
// (wo1/q2/wo2/wf, 64x128 tile): 8-wave 512thr -> 16-wave 1024thr
// (GWM4 GWN4 WM1 WN2), grid 512 unchanged -> 2 blk/CU x 16 = 32 waves/CU
// (max). Register budget (unified VGPR+AGPR, R12 lesson): acc 8 + fa 4 +
// fb 8 + addr ~30 = ~50 <= 64 cap at MW=8 -> no spill. GEGLU NOT converted:
// its 16-wave variant needs ~82 regs > 64 cap -> would spill (R12 signature);
// frozen at R14 config. QKV frozen at R16 (24 waves/CU, 16-wave variant is
// reg-borderline). attn frozen at R15.
// ---------------------------------------------------------------------------

typedef _Float16 half8 __attribute__((ext_vector_type(8)));
typedef float f32x4 __attribute__((ext_vector_type(4)));

__device__ __forceinline__ f32x4 mfma16(half8 a, half8 b, f32x4 c) {
  return __builtin_amdgcn_mfma_f32_16x16x32_f16(a, b, c, 0, 0, 0);
}

__device__ __forceinline__ void gload16(const _Float16* g, _Float16* l) {
  __builtin_amdgcn_global_load_lds(
      (const __attribute__((address_space(1))) void*)g,
      (__attribute__((address_space(3))) void*)l, 16, 0, 0);
}

template <int N>
__device__ __forceinline__ void wait_vmcnt() {
  if constexpr (N == 0)
    asm volatile("s_waitcnt vmcnt(0)" ::: "memory");
  else if constexpr (N == 1)
    asm volatile("s_waitcnt vmcnt(1)" ::: "memory");
  else if constexpr (N == 2)
    asm volatile("s_waitcnt vmcnt(2)" ::: "memory");
  else if constexpr (N == 3)
    asm volatile("s_waitcnt vmcnt(3)" ::: "memory");
  else if constexpr (N == 4)
    asm volatile("s_waitcnt vmcnt(4)" ::: "memory");
  else
    static_assert(N <= 4, "add a case");
}

// ---------------- fused prep: 10 weight transposes + enc cvt + LN1 ---------
struct PrepArgs {
  const float* src[10];
  _Float16* dst[10];
  int K[10], N[10], base[10];
  const float* enc;
  _Float16* ench;
  int encBase, nEnc;
  const float* x;
  const float* ln1g;
  const float* ln1b;
  _Float16* hbuf;
  int lnBase;  // first block index of LN rows (8192 rows follow)
};

__global__ __launch_bounds__(256)
void prep_all(PrepArgs pa) {
  __shared__ float tile[32][33];
  const int bid = blockIdx.x;
  const int tx = threadIdx.x, ty = threadIdx.y;
  const int t = ty * 32 + tx;
  if (bid >= pa.lnBase) {
    // -------- LayerNorm1 row --------
    const int row = bid - pa.lnBase;
    const float* xr = pa.x + (size_t)row * 512;
    float v0 = xr[t], v1 = xr[t + 256];
    float s1 = v0 + v1, s2 = v0 * v0 + v1 * v1;
    #pragma unroll
    for (int m = 32; m >= 1; m >>= 1) {
      s1 += __shfl_xor(s1, m);
      s2 += __shfl_xor(s2, m);
    }
    __shared__ float red[8];
    if ((t & 63) == 0) { red[t >> 6] = s1; red[4 + (t >> 6)] = s2; }
    __syncthreads();
    s1 = red[0] + red[1] + red[2] + red[3];
    s2 = red[4] + red[5] + red[6] + red[7];
    const float mu = s1 * (1.0f / 512.0f);
    const float var = s2 * (1.0f / 512.0f) - mu * mu;
    const float rs = rsqrtf(var + 1e-5f);
    pa.hbuf[(size_t)row * 512 + t] =
        (_Float16)((v0 - mu) * rs * pa.ln1g[t] + pa.ln1b[t]);
    pa.hbuf[(size_t)row * 512 + t + 256] =
        (_Float16)((v1 - mu) * rs * pa.ln1g[t + 256] + pa.ln1b[t + 256]);
    return;
  }
  if (bid >= pa.encBase) {
    const int i = (bid - pa.encBase) * 256 + t;
    if (i < pa.nEnc) pa.ench[i] = (_Float16)pa.enc[i];
    return;
  }
  int mi = 0;
  #pragma unroll
  for (int j = 1; j < 10; j++)
    if (bid >= pa.base[j]) mi = j;
  const int K = pa.K[mi], N = pa.N[mi];
  const int rel = bid - pa.base[mi];
  const int ntiles = N >> 5;
  const int bx = rel % ntiles, by = rel / ntiles;
  const float* src = pa.src[mi];
  _Float16* dst = pa.dst[mi];
  const int n0 = bx * 32, k0 = by * 32;
  #pragma unroll
  for (int j = ty; j < 32; j += 8)
    tile[j][tx] = src[(size_t)(k0 + j) * N + n0 + tx];
  __syncthreads();
  #pragma unroll
  for (int j = ty; j < 32; j += 8)
    dst[(size_t)(n0 + j) * K + k0 + tx] = (_Float16)tile[tx][j];
}

// ---------------- V transpose: [b*S+s][h*64+d] -> [(bh*64)+d][s] -----------
__global__ __launch_bounds__(256)
void vt_kernel(const _Float16* __restrict__ src, _Float16* __restrict__ dst,
               int S, int srcStride, int dstStride) {
  __shared__ _Float16 tile[32][33];
  const int tx = threadIdx.x, ty = threadIdx.y;  // (32,8)
  const int s0 = blockIdx.x * 32, d0 = blockIdx.y * 32, bh = blockIdx.z;
  const int b = bh >> 3, h = bh & 7;
  const _Float16* sp = src + (size_t)b * S * srcStride + h * 64 + d0;
  #pragma unroll
  for (int j = ty; j < 32; j += 8) {
    int s = s0 + j; if (s >= S) s = S - 1;
    tile[j][tx] = sp[(size_t)s * srcStride + tx];
  }
  __syncthreads();
  _Float16* dp = dst + ((size_t)bh * 64 + d0) * dstStride + s0;
  #pragma unroll
  for (int j = ty; j < 32; j += 8)
    dp[(size_t)j * dstStride + tx] = tile[tx][j];
}

// ---------------- LayerNorm (row=512), fp32 in -> f16 out ------------------
__global__ __launch_bounds__(256)
void ln_kernel(const float* __restrict__ x, const float* __restrict__ g,
               const float* __restrict__ b, _Float16* __restrict__ out) {
  const int row = blockIdx.x, t = threadIdx.x;
  const float* xr = x + (size_t)row * 512;
  float v0 = xr[t], v1 = xr[t + 256];
  float s1 = v0 + v1, s2 = v0 * v0 + v1 * v1;
  #pragma unroll
  for (int m = 32; m >= 1; m >>= 1) {
    s1 += __shfl_xor(s1, m);
    s2 += __shfl_xor(s2, m);
  }
  __shared__ float red[8];
  if ((t & 63) == 0) { red[t >> 6] = s1; red[4 + (t >> 6)] = s2; }
  __syncthreads();
  s1 = red[0] + red[1] + red[2] + red[3];
  s2 = red[4] + red[5] + red[6] + red[7];
  const float mu = s1 * (1.0f / 512.0f);
  const float var = s2 * (1.0f / 512.0f) - mu * mu;
  const float rs = rsqrtf(var + 1e-5f);
  out[(size_t)row * 512 + t] = (_Float16)((v0 - mu) * rs * g[t] + b[t]);
  out[(size_t)row * 512 + t + 256] =
      (_Float16)((v1 - mu) * rs * g[t + 256] + b[t + 256]);
}

// ---------------- GEMM: C = A[M,K] @ BT[N,K]^T, XCD swizzle ----------------
// PIPE=0: 2-buffer __syncthreads loop. PIPE=1: 3-buffer counted-vmcnt.
// EPI 0: f16 store. EPI 1: Cf = resid + acc + bias. EPI 2: GEGLU dual.
template <int EPI, int GWM, int GWN, int WM, int WN, int MW, int SWZ,
          int PIPE>
__global__ __launch_bounds__(GWM * GWN * 64, MW)
void gemm_bt(const _Float16* __restrict__ A, const _Float16* __restrict__ BT,
             int M, int N, int K, int lda, int ldb, int ldc,
             _Float16* Ch, float* Cf,
             const float* __restrict__ bias, const float* resid) {
  constexpr int NW = GWM * GWN;
  constexpr int BM = GWM * WM * 16;
  constexpr int BN = GWN * WN * 16;
  constexpr int NBUF = PIPE ? 3 : 2;
  // per-thread global_load_lds per stage (uniform across threads)
  constexpr int LPT = (BM / 16) / NW + ((BN / 16) / NW) * ((EPI == 2) ? 2 : 1);
  __shared__ __align__(16) _Float16 As[NBUF][4 * BM * 8];
  __shared__ __align__(16) _Float16 Bs[NBUF][4 * BN * 8];
  __shared__ __align__(16) _Float16 Bs2[(EPI == 2) ? NBUF : 1]
                                      [(EPI == 2) ? 4 * BN * 8 : 8];

  const int t = threadIdx.x;
  const int NNB = (N + BN - 1) / BN;
  int bm, bn;
  if constexpr (SWZ) {
    const int MG = (M / BM) >> 3;
    const int xcd = blockIdx.x & 7;
    const int s = blockIdx.x >> 3;
    bm = xcd * MG + s % MG;
    bn = s / MG;
  } else {
    bn = blockIdx.x % NNB;
    bm = blockIdx.x / NNB;
  }
  const int m0 = bm * BM, n0 = bn * BN;
  const int lane = t & 63, wv = t >> 6;
  const int quad = lane >> 4, l15 = lane & 15;
  const int wm = wv / GWN, wn = wv % GWN;

  f32x4 zero4 = {0.f, 0.f, 0.f, 0.f};
  f32x4 acc[WM][WN];
  f32x4 acc2[(EPI == 2) ? WM : 1][(EPI == 2) ? WN : 1];
  #pragma unroll
  for (int mi = 0; mi < WM; mi++)
    #pragma unroll
    for (int ni = 0; ni < WN; ni++) acc[mi][ni] = zero4;
  if constexpr (EPI == 2) {
    #pragma unroll
    for (int mi = 0; mi < WM; mi++)
      #pragma unroll
      for (int ni = 0; ni < WN; ni++) acc2[mi][ni] = zero4;
  }

  auto stageAll = [&](int k0, int pb) {
    #pragma unroll
    for (int c = wv; c < BM / 16; c += NW) {
      const int s = c * 64 + lane;
      const int q = s / BM;
      const int r = s % BM;
      int rg = m0 + r; if (rg >= M) rg = M - 1;
      gload16(A + (size_t)rg * lda + k0 + q * 8, &As[pb][c * 512]);
    }
    #pragma unroll
    for (int c = wv; c < BN / 16; c += NW) {
      const int s = c * 64 + lane;
      const int q = s / BN;
      const int r = s % BN;
      gload16(BT + (size_t)(n0 + r) * ldb + k0 + q * 8, &Bs[pb][c * 512]);
      if constexpr (EPI == 2)
        gload16(BT + (size_t)(2048 + n0 + r) * ldb + k0 + q * 8,
                &Bs2[pb][c * 512]);
    }
  };

  auto computeTile = [&](int cur) {
    half8 fa[WM], fb[WN], fb2[(EPI == 2) ? WN : 1];
    #pragma unroll
    for (int mi = 0; mi < WM; mi++)
      fa[mi] = *(const half8*)(&As[cur]
          [((size_t)quad * BM + wm * WM * 16 + mi * 16 + l15) * 8]);
    #pragma unroll
    for (int ni = 0; ni < WN; ni++) {
      fb[ni] = *(const half8*)(&Bs[cur]
          [((size_t)quad * BN + wn * WN * 16 + ni * 16 + l15) * 8]);
      if constexpr (EPI == 2)
        fb2[ni] = *(const half8*)(&Bs2[cur]
            [((size_t)quad * BN + wn * WN * 16 + ni * 16 + l15) * 8]);
    }
    if constexpr (PIPE) __builtin_amdgcn_s_setprio(1);
    #pragma unroll
    for (int mi = 0; mi < WM; mi++)
      #pragma unroll
      for (int ni = 0; ni < WN; ni++) {
        acc[mi][ni] = mfma16(fa[mi], fb[ni], acc[mi][ni]);
        if constexpr (EPI == 2)
          acc2[mi][ni] = mfma16(fa[mi], fb2[ni], acc2[mi][ni]);
      }
    if constexpr (PIPE) __builtin_amdgcn_s_setprio(0);
  };

  const int NIT = K >> 5;
  if constexpr (PIPE) {
    // 3-buffer stage-ahead-2, counted vmcnt.
    stageAll(0, 0);
    if (NIT > 1) stageAll(32, 1);
    int cur = 0, pre = 2;
    for (int it = 0; it < NIT; ++it) {
      if (it + 1 < NIT) wait_vmcnt<LPT>();
      else wait_vmcnt<0>();
      __builtin_amdgcn_s_barrier();
      __builtin_amdgcn_sched_barrier(0);
      computeTile(cur);
      asm volatile("s_waitcnt lgkmcnt(0)" ::: "memory");
      __builtin_amdgcn_sched_barrier(0);
      __builtin_amdgcn_s_barrier();
      if (it + 2 < NIT) stageAll((it + 2) << 5, pre);
      cur = (cur == 2) ? 0 : cur + 1;
      pre = (pre == 2) ? 0 : pre + 1;
    }
  } else {
    // 2-buffer __syncthreads loop.
    stageAll(0, 0);
    __syncthreads();
    for (int it = 0; it < NIT; ++it) {
      const int cur = it & 1;
      if (it + 1 < NIT) stageAll((it + 1) << 5, cur ^ 1);
      computeTile(cur);
      __syncthreads();
    }
  }

  #pragma unroll
  for (int mi = 0; mi < WM; mi++) {
    const int rbase = m0 + wm * WM * 16 + mi * 16 + quad * 4;
    #pragma unroll
    for (int r = 0; r < 4; r++) {
      const int row = rbase + r;
      if (row >= M) continue;
      #pragma unroll
      for (int ni = 0; ni < WN; ni++) {
        const int col = n0 + wn * WN * 16 + ni * 16 + l15;
        const float v = acc[mi][ni][r];
        if constexpr (EPI == 0) {
          Ch[(size_t)row * ldc + col] = (_Float16)v;
        } else if constexpr (EPI == 1) {
          Cf[(size_t)row * ldc + col] =
              resid[(size_t)row * ldc + col] + v + bias[col];
        } else {
          const float u = v + bias[col];
          const float gg = acc2[mi][ni][r] + bias[col + 2048];
          const float ge = 0.5f * gg * (1.0f + erff(gg * 0.70710678118f));
          Ch[(size_t)row * ldc + col] = (_Float16)(u * ge);
        }
      }
    }
  }
}

// ---------------- flash attention v2: 8 waves x 16 Q-rows, 3-buffer --------
// 512 threads. Waves 0-3 stage K tile (32sk x 64d), waves 4-7 stage VT tile
// (64d x 32sk); 1 gload16/thread/stage. Grid (Sq/128, B*H) -> 16 waves/CU.
__global__ __launch_bounds__(512)
void attn2(const _Float16* __restrict__ Q, const _Float16* __restrict__ K,
           const _Float16* __restrict__ VT, _Float16* __restrict__ O,
           int qStride, int kStride, long kBatchStride,
           int vtStride, int Sk) {
  __shared__ __align__(16) _Float16 KsL[3][2048];
  __shared__ __align__(16) _Float16 VTsL[3][2048];
  __shared__ __align__(16) _Float16 Ps[8][16][40];

  const int t = threadIdx.x;
  const int w = t >> 6, lane = t & 63, quad = lane >> 4, l15 = lane & 15;
  const int bh = blockIdx.y, b = bh >> 3, h = bh & 7;
  const int q0 = blockIdx.x * 128 + w * 16;

  const _Float16 qscale = (_Float16)(0.125f * 1.44269504f);
  half8 qf[2];
  #pragma unroll
  for (int c = 0; c < 2; c++) {
    const _Float16* qp = Q + (size_t)(b * 1024 + q0 + l15) * qStride +
                         h * 64 + c * 32 + quad * 8;
    half8 v = *(const half8*)qp;
    #pragma unroll
    for (int j = 0; j < 8; j++) v[j] *= qscale;
    qf[c] = v;
  }

  f32x4 zero4 = {0.f, 0.f, 0.f, 0.f};
  f32x4 oa[4];
  float psum[4];
  #pragma unroll
  for (int nt = 0; nt < 4; nt++) oa[nt] = zero4;
  #pragma unroll
  for (int r = 0; r < 4; r++) psum[r] = 0.f;

  const _Float16* kp = K + (size_t)b * kBatchStride + h * 64;
  const _Float16* vtp = VT + (size_t)bh * 64 * vtStride;
  const bool doK = (t < 256);               // wave-uniform
  const int ts = doK ? t : t - 256;
  const int ksk = ts & 31, kc = ts >> 7, kqd = (ts >> 5) & 3;
  const int vd = ts & 63, vqd = ts >> 6;

  auto stageKV = [&](int skb, int pb) {
    if (doK) {
      int skc = skb + ksk; if (skc >= Sk) skc = Sk - 1;
      gload16(kp + (size_t)skc * kStride + kc * 32 + kqd * 8,
              &KsL[pb][ts * 8]);
    } else {
      gload16(vtp + (size_t)vd * vtStride + skb + vqd * 8,
              &VTsL[pb][ts * 8]);
    }
  };

  const int NITa = (Sk + 31) >> 5;
  stageKV(0, 0);
  if (NITa > 1) stageKV(32, 1);

  int cur = 0, pre = 2;
  int it = 0;
  for (int skb = 0; skb < Sk; skb += 32, ++it) {
    if (it + 1 < NITa) wait_vmcnt<1>();
    else wait_vmcnt<0>();
    __builtin_amdgcn_s_barrier();
    __builtin_amdgcn_sched_barrier(0);

    const bool tail = (skb + 32 > Sk);
    #pragma unroll
    for (int ct = 0; ct < 2; ct++) {
      f32x4 s = zero4;
      half8 kb0 = *(const half8*)(&KsL[cur][(quad * 32 + ct * 16 + l15) * 8]);
      half8 kb1 =
          *(const half8*)(&KsL[cur][(128 + quad * 32 + ct * 16 + l15) * 8]);
      s = mfma16(qf[0], kb0, s);
      s = mfma16(qf[1], kb1, s);
      if (tail) {
        const bool valid = (skb + ct * 16 + l15) < Sk;
        #pragma unroll
        for (int r = 0; r < 4; r++)
          if (!valid) s[r] = -__builtin_inff();
      }
      #pragma unroll
      for (int r = 0; r < 4; r++) {
        const float e = exp2f(s[r]);
        psum[r] += e;
        Ps[w][quad * 4 + r][ct * 16 + l15] = (_Float16)e;
      }
    }
    {
      const half8 pf = *(const half8*)(&Ps[w][l15][quad * 8]);
      #pragma unroll
      for (int nt = 0; nt < 4; nt++) {
        const half8 vf =
            *(const half8*)(&VTsL[cur][(quad * 64 + nt * 16 + l15) * 8]);
        oa[nt] = mfma16(pf, vf, oa[nt]);
      }
    }

    asm volatile("s_waitcnt lgkmcnt(0)" ::: "memory");
    __builtin_amdgcn_sched_barrier(0);
    __builtin_amdgcn_s_barrier();
    if (it + 2 < NITa) stageKV(skb + 64, pre);
    cur = (cur == 2) ? 0 : cur + 1;
    pre = (pre == 2) ? 0 : pre + 1;
  }

  #pragma unroll
  for (int r = 0; r < 4; r++) {
    #pragma unroll
    for (int mm = 1; mm < 16; mm <<= 1)
      psum[r] += __shfl_xor(psum[r], mm);
    psum[r] = 1.0f / psum[r];
  }

  #pragma unroll
  for (int nt = 0; nt < 4; nt++)
    #pragma unroll
    for (int r = 0; r < 4; r++) {
      const size_t row = (size_t)(b * 1024 + q0 + quad * 4 + r);
      O[row * 512 + h * 64 + nt * 16 + l15] =
          (_Float16)(oa[nt][r] * psum[r]);
    }
}

// ---------------------------------------------------------------------------
extern "C" void kernel_launch(void* const* d_in, const int* in_sizes, int n_in,
                              void* d_out, int out_size, void* d_ws,
                              size_t ws_size, hipStream_t stream) {
  const float* x    = (const float*)d_in[0];
  const float* enc  = (const float*)d_in[1];
  const float* ln1g = (const float*)d_in[2];
  const float* ln1b = (const float*)d_in[3];
  const float* wq1  = (const float*)d_in[4];
  const float* wk1  = (const float*)d_in[5];
  const float* wv1  = (const float*)d_in[6];
  const float* wo1  = (const float*)d_in[7];
  const float* bo1  = (const float*)d_in[8];
  const float* ln2g = (const float*)d_in[9];
  const float* ln2b = (const float*)d_in[10];
  const float* wq2  = (const float*)d_in[11];
  const float* wk2  = (const float*)d_in[12];
  const float* wv2  = (const float*)d_in[13];
  const float* wo2  = (const float*)d_in[14];
  const float* bo2  = (const float*)d_in[15];
  const float* ln3g = (const float*)d_in[16];
  const float* ln3b = (const float*)d_in[17];
  const float* wg   = (const float*)d_in[18];
  const float* bg   = (const float*)d_in[19];
  const float* wf   = (const float*)d_in[20];
  const float* bfp  = (const float*)d_in[21];
  float* out = (float*)d_out;

  char* ws = (char*)d_ws;
  _Float16* qkvT  = (_Float16*)(ws + 0);         // [1536,512]
  _Float16* q2T   = (_Float16*)(ws + 1572864);   // [512,512]
  _Float16* kv2T  = (_Float16*)(ws + 2097152);   // [1024,768]
  _Float16* wo1T  = (_Float16*)(ws + 3670016);   // [512,512]
  _Float16* wo2T  = (_Float16*)(ws + 4194304);   // [512,512]
  _Float16* wgT   = (_Float16*)(ws + 4718592);   // [4096,512]
  _Float16* wfT   = (_Float16*)(ws + 8912896);   // [512,2048]
  _Float16* hbuf  = (_Float16*)(ws + 11010048);  // [8192,512] (VTself in attn1)
  _Float16* qkv   = (_Float16*)(ws + 19398656);  // [8192,1536]
  _Float16* q2b   = (_Float16*)(ws + 44564480);  // [8192,512]
  _Float16* kv2b  = (_Float16*)(ws + 52953088);  // [616,1024]
  _Float16* attnb = (_Float16*)(ws + 54214656);  // [8192,512]
  _Float16* ench  = (_Float16*)(ws + 62603264);  // [616,768]
  _Float16* ffb   = (_Float16*)(ws + 19398656);  // [8192,2048] aliases qkv+q2b
  _Float16* VTself = hbuf;                       // [4096,1024]
  _Float16* VTc   = (_Float16*)(ws + 62603264);  // [4096,96] over ench (dead
                                                 // after kv2 GEMM)

  // ---- fused prep: weights + enc + LN1 (one launch) ----
  PrepArgs pa;
  const float* srcs[10] = {wq1, wk1, wv1, wo1, wq2, wk2, wv2, wo2, wg, wf};
  _Float16* dsts[10] = {qkvT, qkvT + 512 * 512, qkvT + 1024 * 512, wo1T, q2T,
                        kv2T, kv2T + 512 * 768, wo2T, wgT, wfT};
  const int Ks[10] = {512, 512, 512, 512, 512, 768, 768, 512, 512, 2048};
  const int Ns[10] = {512, 512, 512, 512, 512, 512, 512, 512, 4096, 512};
  int base = 0;
  for (int i = 0; i < 10; i++) {
    pa.src[i] = srcs[i]; pa.dst[i] = dsts[i];
    pa.K[i] = Ks[i]; pa.N[i] = Ns[i]; pa.base[i] = base;
    base += (Ks[i] >> 5) * (Ns[i] >> 5);
  }
  pa.enc = enc; pa.ench = ench; pa.encBase = base; pa.nEnc = 473088;
  base += (473088 + 255) / 256;
  pa.x = x; pa.ln1g = ln1g; pa.ln1b = ln1b; pa.hbuf = hbuf; pa.lnBase = base;
  base += 8192;
  prep_all<<<base, dim3(32, 8), 0, stream>>>(pa);

  const dim3 tb(32, 8);

  // ---- self-attention block ----
  // QKV: 128x128 tile, 8 waves, grid 768 (R16)
  gemm_bt<0, 2, 4, 4, 2, 4, 1, 0><<<768, 512, 0, stream>>>(
      hbuf, qkvT, 8192, 1536, 512, 512, 512, 1536,
      qkv, nullptr, nullptr, nullptr);
  vt_kernel<<<dim3(32, 2, 64), tb, 0, stream>>>(qkv + 1024, VTself, 1024,
                                                1536, 1024);
  attn2<<<dim3(8, 64), 512, 0, stream>>>(qkv, qkv + 512, VTself, attnb,
                                         1536, 1536, (long)1024 * 1536,
                                         1024, 1024);
  // wo1: 64x128 tile, 16 waves (was 8), grid 512 -> 32 waves/CU
  gemm_bt<1, 4, 4, 1, 2, 8, 1, 0><<<512, 1024, 0, stream>>>(
      attnb, wo1T, 8192, 512, 512, 512, 512, 512, nullptr, out, bo1, x);

  // ---- cross-attention block ----
  ln_kernel<<<8192, 256, 0, stream>>>(out, ln2g, ln2b, hbuf);
  gemm_bt<0, 4, 4, 1, 2, 8, 1, 0><<<512, 1024, 0, stream>>>(
      hbuf, q2T, 8192, 512, 512, 512, 512, 512,
      q2b, nullptr, nullptr, nullptr);
  gemm_bt<0, 1, 4, 4, 2, 4, 0, 1><<<80, 256, 0, stream>>>(
      ench, kv2T, 616, 1024, 768, 768, 768, 1024,
      kv2b, nullptr, nullptr, nullptr);
  vt_kernel<<<dim3(3, 2, 64), tb, 0, stream>>>(kv2b + 512, VTc, 77, 1024, 96);
  attn2<<<dim3(8, 64), 512, 0, stream>>>(q2b, kv2b, VTc, attnb,
                                         512, 1024, (long)77 * 1024, 96, 77);
  gemm_bt<1, 4, 4, 1, 2, 8, 1, 0><<<512, 1024, 0, stream>>>(
      attnb, wo2T, 8192, 512, 512, 512, 512, 512, nullptr, out, bo2, out);

  // ---- GEGLU feed-forward ----
  ln_kernel<<<8192, 256, 0, stream>>>(out, ln3g, ln3b, hbuf);
  // GEGLU: 128x128-dual, 8 waves (R14; 16-wave variant would spill, frozen)
  gemm_bt<2, 2, 4, 4, 2, 4, 1, 0><<<1024, 512, 0, stream>>>(
      hbuf, wgT, 8192, 2048, 512, 512, 512, 2048,
      ffb, nullptr, bg, nullptr);
  // wf: 64x128 tile, 16 waves (was 8), grid 512 -> 32 waves/CU
  gemm_bt<1, 4, 4, 1, 2, 8, 1, 0><<<512, 1024, 0, stream>>>(
      ffb, wfT, 8192, 512, 2048, 2048, 2048, 512,
      nullptr, out, bfp, out);
}

// Round 9
// 418.327 us; speedup vs baseline: 1.0972x; 1.0138x over previous
//
#include <hip/hip_runtime.h>

// ---------------------------------------------------------------------------
// BasicTransformerBlock on MI355X (gfx950).
// R18: (a) GEGLU epilogue erff -> tanh-GELU (erff ~25-30 VALU ops x 32
// outputs/thread ~= the whole K-loop's MFMA cost; VALUBusy 24% > MfmaUtil 16%
// is the signature). tanh form: 1 v_exp + 1 v_rcp + ~6 fma; adds <=~5e-4 to
// absmax (tolerance 0.0156). (b) q2+kv2 merged into one 592-block launch
// (kv2 alone = 80 blocks = 31% CU fill, pure tail) via shared gemm_body
// device template with runtime swz. Everything else frozen at R17
// (occupancy ladder saturating: -15.5/-12.6/-6.8 over R15-R17).
// ---------------------------------------------------------------------------

typedef _Float16 half8 __attribute__((ext_vector_type(8)));
typedef float f32x4 __attribute__((ext_vector_type(4)));

__device__ __forceinline__ f32x4 mfma16(half8 a, half8 b, f32x4 c) {
  return __builtin_amdgcn_mfma_f32_16x16x32_f16(a, b, c, 0, 0, 0);
}

__device__ __forceinline__ void gload16(const _Float16* g, _Float16* l) {
  __builtin_amdgcn_global_load_lds(
      (const __attribute__((address_space(1))) void*)g,
      (__attribute__((address_space(3))) void*)l, 16, 0, 0);
}

template <int N>
__device__ __forceinline__ void wait_vmcnt() {
  if constexpr (N == 0)
    asm volatile("s_waitcnt vmcnt(0)" ::: "memory");
  else if constexpr (N == 1)
    asm volatile("s_waitcnt vmcnt(1)" ::: "memory");
  else if constexpr (N == 2)
    asm volatile("s_waitcnt vmcnt(2)" ::: "memory");
  else if constexpr (N == 3)
    asm volatile("s_waitcnt vmcnt(3)" ::: "memory");
  else if constexpr (N == 4)
    asm volatile("s_waitcnt vmcnt(4)" ::: "memory");
  else
    static_assert(N <= 4, "add a case");
}

// ---------------- fused prep: 10 weight transposes + enc cvt + LN1 ---------
struct PrepArgs {
  const float* src[10];
  _Float16* dst[10];
  int K[10], N[10], base[10];
  const float* enc;
  _Float16* ench;
  int encBase, nEnc;
  const float* x;
  const float* ln1g;
  const float* ln1b;
  _Float16* hbuf;
  int lnBase;  // first block index of LN rows (8192 rows follow)
};

__global__ __launch_bounds__(256)
void prep_all(PrepArgs pa) {
  __shared__ float tile[32][33];
  const int bid = blockIdx.x;
  const int tx = threadIdx.x, ty = threadIdx.y;
  const int t = ty * 32 + tx;
  if (bid >= pa.lnBase) {
    // -------- LayerNorm1 row --------
    const int row = bid - pa.lnBase;
    const float* xr = pa.x + (size_t)row * 512;
    float v0 = xr[t], v1 = xr[t + 256];
    float s1 = v0 + v1, s2 = v0 * v0 + v1 * v1;
    #pragma unroll
    for (int m = 32; m >= 1; m >>= 1) {
      s1 += __shfl_xor(s1, m);
      s2 += __shfl_xor(s2, m);
    }
    __shared__ float red[8];
    if ((t & 63) == 0) { red[t >> 6] = s1; red[4 + (t >> 6)] = s2; }
    __syncthreads();
    s1 = red[0] + red[1] + red[2] + red[3];
    s2 = red[4] + red[5] + red[6] + red[7];
    const float mu = s1 * (1.0f / 512.0f);
    const float var = s2 * (1.0f / 512.0f) - mu * mu;
    const float rs = rsqrtf(var + 1e-5f);
    pa.hbuf[(size_t)row * 512 + t] =
        (_Float16)((v0 - mu) * rs * pa.ln1g[t] + pa.ln1b[t]);
    pa.hbuf[(size_t)row * 512 + t + 256] =
        (_Float16)((v1 - mu) * rs * pa.ln1g[t + 256] + pa.ln1b[t + 256]);
    return;
  }
  if (bid >= pa.encBase) {
    const int i = (bid - pa.encBase) * 256 + t;
    if (i < pa.nEnc) pa.ench[i] = (_Float16)pa.enc[i];
    return;
  }
  int mi = 0;
  #pragma unroll
  for (int j = 1; j < 10; j++)
    if (bid >= pa.base[j]) mi = j;
  const int K = pa.K[mi], N = pa.N[mi];
  const int rel = bid - pa.base[mi];
  const int ntiles = N >> 5;
  const int bx = rel % ntiles, by = rel / ntiles;
  const float* src = pa.src[mi];
  _Float16* dst = pa.dst[mi];
  const int n0 = bx * 32, k0 = by * 32;
  #pragma unroll
  for (int j = ty; j < 32; j += 8)
    tile[j][tx] = src[(size_t)(k0 + j) * N + n0 + tx];
  __syncthreads();
  #pragma unroll
  for (int j = ty; j < 32; j += 8)
    dst[(size_t)(n0 + j) * K + k0 + tx] = (_Float16)tile[tx][j];
}

// ---------------- V transpose: [b*S+s][h*64+d] -> [(bh*64)+d][s] -----------
__global__ __launch_bounds__(256)
void vt_kernel(const _Float16* __restrict__ src, _Float16* __restrict__ dst,
               int S, int srcStride, int dstStride) {
  __shared__ _Float16 tile[32][33];
  const int tx = threadIdx.x, ty = threadIdx.y;  // (32,8)
  const int s0 = blockIdx.x * 32, d0 = blockIdx.y * 32, bh = blockIdx.z;
  const int b = bh >> 3, h = bh & 7;
  const _Float16* sp = src + (size_t)b * S * srcStride + h * 64 + d0;
  #pragma unroll
  for (int j = ty; j < 32; j += 8) {
    int s = s0 + j; if (s >= S) s = S - 1;
    tile[j][tx] = sp[(size_t)s * srcStride + tx];
  }
  __syncthreads();
  _Float16* dp = dst + ((size_t)bh * 64 + d0) * dstStride + s0;
  #pragma unroll
  for (int j = ty; j < 32; j += 8)
    dp[(size_t)j * dstStride + tx] = tile[tx][j];
}

// ---------------- LayerNorm (row=512), fp32 in -> f16 out ------------------
__global__ __launch_bounds__(256)
void ln_kernel(const float* __restrict__ x, const float* __restrict__ g,
               const float* __restrict__ b, _Float16* __restrict__ out) {
  const int row = blockIdx.x, t = threadIdx.x;
  const float* xr = x + (size_t)row * 512;
  float v0 = xr[t], v1 = xr[t + 256];
  float s1 = v0 + v1, s2 = v0 * v0 + v1 * v1;
  #pragma unroll
  for (int m = 32; m >= 1; m >>= 1) {
    s1 += __shfl_xor(s1, m);
    s2 += __shfl_xor(s2, m);
  }
  __shared__ float red[8];
  if ((t & 63) == 0) { red[t >> 6] = s1; red[4 + (t >> 6)] = s2; }
  __syncthreads();
  s1 = red[0] + red[1] + red[2] + red[3];
  s2 = red[4] + red[5] + red[6] + red[7];
  const float mu = s1 * (1.0f / 512.0f);
  const float var = s2 * (1.0f / 512.0f) - mu * mu;
  const float rs = rsqrtf(var + 1e-5f);
  out[(size_t)row * 512 + t] = (_Float16)((v0 - mu) * rs * g[t] + b[t]);
  out[(size_t)row * 512 + t + 256] =
      (_Float16)((v1 - mu) * rs * g[t + 256] + b[t + 256]);
}

// ---------------- GEMM body: C = A[M,K] @ BT[N,K]^T ------------------------
// PIPE=0: 2-buffer __syncthreads loop. PIPE=1: 3-buffer counted-vmcnt.
// EPI 0: f16 store. EPI 1: Cf = resid + acc + bias. EPI 2: GEGLU dual
// (tanh-GELU). swz: runtime XCD swizzle flag.
template <int EPI, int GWM, int GWN, int WM, int WN, int PIPE>
__device__ __forceinline__ void gemm_body(
    int bid, int swz,
    const _Float16* A, const _Float16* BT,
    int M, int N, int K, int lda, int ldb, int ldc,
    _Float16* Ch, float* Cf, const float* bias, const float* resid) {
  constexpr int NW = GWM * GWN;
  constexpr int BM = GWM * WM * 16;
  constexpr int BN = GWN * WN * 16;
  constexpr int NBUF = PIPE ? 3 : 2;
  constexpr int LPT = (BM / 16) / NW + ((BN / 16) / NW) * ((EPI == 2) ? 2 : 1);
  __shared__ __align__(16) _Float16 As[NBUF][4 * BM * 8];
  __shared__ __align__(16) _Float16 Bs[NBUF][4 * BN * 8];
  __shared__ __align__(16) _Float16 Bs2[(EPI == 2) ? NBUF : 1]
                                      [(EPI == 2) ? 4 * BN * 8 : 8];

  const int t = threadIdx.x;
  const int NNB = (N + BN - 1) / BN;
  int bm, bn;
  if (swz) {
    const int MG = (M / BM) >> 3;
    const int xcd = bid & 7;
    const int s = bid >> 3;
    bm = xcd * MG + s % MG;
    bn = s / MG;
  } else {
    bn = bid % NNB;
    bm = bid / NNB;
  }
  const int m0 = bm * BM, n0 = bn * BN;
  const int lane = t & 63, wv = t >> 6;
  const int quad = lane >> 4, l15 = lane & 15;
  const int wm = wv / GWN, wn = wv % GWN;

  f32x4 zero4 = {0.f, 0.f, 0.f, 0.f};
  f32x4 acc[WM][WN];
  f32x4 acc2[(EPI == 2) ? WM : 1][(EPI == 2) ? WN : 1];
  #pragma unroll
  for (int mi = 0; mi < WM; mi++)
    #pragma unroll
    for (int ni = 0; ni < WN; ni++) acc[mi][ni] = zero4;
  if constexpr (EPI == 2) {
    #pragma unroll
    for (int mi = 0; mi < WM; mi++)
      #pragma unroll
      for (int ni = 0; ni < WN; ni++) acc2[mi][ni] = zero4;
  }

  auto stageAll = [&](int k0, int pb) {
    #pragma unroll
    for (int c = wv; c < BM / 16; c += NW) {
      const int s = c * 64 + lane;
      const int q = s / BM;
      const int r = s % BM;
      int rg = m0 + r; if (rg >= M) rg = M - 1;
      gload16(A + (size_t)rg * lda + k0 + q * 8, &As[pb][c * 512]);
    }
    #pragma unroll
    for (int c = wv; c < BN / 16; c += NW) {
      const int s = c * 64 + lane;
      const int q = s / BN;
      const int r = s % BN;
      gload16(BT + (size_t)(n0 + r) * ldb + k0 + q * 8, &Bs[pb][c * 512]);
      if constexpr (EPI == 2)
        gload16(BT + (size_t)(2048 + n0 + r) * ldb + k0 + q * 8,
                &Bs2[pb][c * 512]);
    }
  };

  auto computeTile = [&](int cur) {
    half8 fa[WM], fb[WN], fb2[(EPI == 2) ? WN : 1];
    #pragma unroll
    for (int mi = 0; mi < WM; mi++)
      fa[mi] = *(const half8*)(&As[cur]
          [((size_t)quad * BM + wm * WM * 16 + mi * 16 + l15) * 8]);
    #pragma unroll
    for (int ni = 0; ni < WN; ni++) {
      fb[ni] = *(const half8*)(&Bs[cur]
          [((size_t)quad * BN + wn * WN * 16 + ni * 16 + l15) * 8]);
      if constexpr (EPI == 2)
        fb2[ni] = *(const half8*)(&Bs2[cur]
            [((size_t)quad * BN + wn * WN * 16 + ni * 16 + l15) * 8]);
    }
    if constexpr (PIPE) __builtin_amdgcn_s_setprio(1);
    #pragma unroll
    for (int mi = 0; mi < WM; mi++)
      #pragma unroll
      for (int ni = 0; ni < WN; ni++) {
        acc[mi][ni] = mfma16(fa[mi], fb[ni], acc[mi][ni]);
        if constexpr (EPI == 2)
          acc2[mi][ni] = mfma16(fa[mi], fb2[ni], acc2[mi][ni]);
      }
    if constexpr (PIPE) __builtin_amdgcn_s_setprio(0);
  };

  const int NIT = K >> 5;
  if constexpr (PIPE) {
    // 3-buffer stage-ahead-2, counted vmcnt.
    stageAll(0, 0);
    if (NIT > 1) stageAll(32, 1);
    int cur = 0, pre = 2;
    for (int it = 0; it < NIT; ++it) {
      if (it + 1 < NIT) wait_vmcnt<LPT>();
      else wait_vmcnt<0>();
      __builtin_amdgcn_s_barrier();
      __builtin_amdgcn_sched_barrier(0);
      computeTile(cur);
      asm volatile("s_waitcnt lgkmcnt(0)" ::: "memory");
      __builtin_amdgcn_sched_barrier(0);
      __builtin_amdgcn_s_barrier();
      if (it + 2 < NIT) stageAll((it + 2) << 5, pre);
      cur = (cur == 2) ? 0 : cur + 1;
      pre = (pre == 2) ? 0 : pre + 1;
    }
  } else {
    // 2-buffer __syncthreads loop.
    stageAll(0, 0);
    __syncthreads();
    for (int it = 0; it < NIT; ++it) {
      const int cur = it & 1;
      if (it + 1 < NIT) stageAll((it + 1) << 5, cur ^ 1);
      computeTile(cur);
      __syncthreads();
    }
  }

  #pragma unroll
  for (int mi = 0; mi < WM; mi++) {
    const int rbase = m0 + wm * WM * 16 + mi * 16 + quad * 4;
    #pragma unroll
    for (int r = 0; r < 4; r++) {
      const int row = rbase + r;
      if (row >= M) continue;
      #pragma unroll
      for (int ni = 0; ni < WN; ni++) {
        const int col = n0 + wn * WN * 16 + ni * 16 + l15;
        const float v = acc[mi][ni][r];
        if constexpr (EPI == 0) {
          Ch[(size_t)row * ldc + col] = (_Float16)v;
        } else if constexpr (EPI == 1) {
          Cf[(size_t)row * ldc + col] =
              resid[(size_t)row * ldc + col] + v + bias[col];
        } else {
          const float u = v + bias[col];
          const float gg = acc2[mi][ni][r] + bias[col + 2048];
          // tanh-approx GELU: 1 exp + 1 rcp + ~6 fma (vs erff ~25-30 ops).
          const float z = 0.7978845608f * gg * (1.0f + 0.044715f * gg * gg);
          const float e2 = exp2f(z * 2.885390082f);   // e^(2z)
          const float th = 1.0f - 2.0f * __builtin_amdgcn_rcpf(e2 + 1.0f);
          const float ge = 0.5f * gg * (1.0f + th);
          Ch[(size_t)row * ldc + col] = (_Float16)(u * ge);
        }
      }
    }
  }
}

template <int EPI, int GWM, int GWN, int WM, int WN, int MW, int SWZ,
          int PIPE>
__global__ __launch_bounds__(GWM * GWN * 64, MW)
void gemm_bt(const _Float16* __restrict__ A, const _Float16* __restrict__ BT,
             int M, int N, int K, int lda, int ldb, int ldc,
             _Float16* Ch, float* Cf,
             const float* __restrict__ bias, const float* resid) {
  gemm_body<EPI, GWM, GWN, WM, WN, PIPE>(blockIdx.x, SWZ, A, BT, M, N, K,
                                         lda, ldb, ldc, Ch, Cf, bias, resid);
}

// Merged q2 (512 swizzled blocks) + kv2 (80 blocks): kv2 alone is 31% CU
// fill; overlapping it under q2 removes a serial tail. Same instantiation
// in both branches -> one LDS allocation; branch is block-uniform.
__global__ __launch_bounds__(1024, 8)
void gemm_q2kv2(const _Float16* hbuf, const _Float16* q2T, _Float16* q2b,
                const _Float16* ench, const _Float16* kv2T, _Float16* kv2b) {
  if (blockIdx.x < 512)
    gemm_body<0, 4, 4, 1, 2, 0>(blockIdx.x, 1, hbuf, q2T,
                                8192, 512, 512, 512, 512, 512,
                                q2b, nullptr, nullptr, nullptr);
  else
    gemm_body<0, 4, 4, 1, 2, 0>(blockIdx.x - 512, 0, ench, kv2T,
                                616, 1024, 768, 768, 768, 1024,
                                kv2b, nullptr, nullptr, nullptr);
}

// ---------------- flash attention v2: 8 waves x 16 Q-rows, 3-buffer --------
// 512 threads. Waves 0-3 stage K tile (32sk x 64d), waves 4-7 stage VT tile
// (64d x 32sk); 1 gload16/thread/stage. Grid (Sq/128, B*H) -> 16 waves/CU.
__global__ __launch_bounds__(512)
void attn2(const _Float16* __restrict__ Q, const _Float16* __restrict__ K,
           const _Float16* __restrict__ VT, _Float16* __restrict__ O,
           int qStride, int kStride, long kBatchStride,
           int vtStride, int Sk) {
  __shared__ __align__(16) _Float16 KsL[3][2048];
  __shared__ __align__(16) _Float16 VTsL[3][2048];
  __shared__ __align__(16) _Float16 Ps[8][16][40];

  const int t = threadIdx.x;
  const int w = t >> 6, lane = t & 63, quad = lane >> 4, l15 = lane & 15;
  const int bh = blockIdx.y, b = bh >> 3, h = bh & 7;
  const int q0 = blockIdx.x * 128 + w * 16;

  const _Float16 qscale = (_Float16)(0.125f * 1.44269504f);
  half8 qf[2];
  #pragma unroll
  for (int c = 0; c < 2; c++) {
    const _Float16* qp = Q + (size_t)(b * 1024 + q0 + l15) * qStride +
                         h * 64 + c * 32 + quad * 8;
    half8 v = *(const half8*)qp;
    #pragma unroll
    for (int j = 0; j < 8; j++) v[j] *= qscale;
    qf[c] = v;
  }

  f32x4 zero4 = {0.f, 0.f, 0.f, 0.f};
  f32x4 oa[4];
  float psum[4];
  #pragma unroll
  for (int nt = 0; nt < 4; nt++) oa[nt] = zero4;
  #pragma unroll
  for (int r = 0; r < 4; r++) psum[r] = 0.f;

  const _Float16* kp = K + (size_t)b * kBatchStride + h * 64;
  const _Float16* vtp = VT + (size_t)bh * 64 * vtStride;
  const bool doK = (t < 256);               // wave-uniform
  const int ts = doK ? t : t - 256;
  const int ksk = ts & 31, kc = ts >> 7, kqd = (ts >> 5) & 3;
  const int vd = ts & 63, vqd = ts >> 6;

  auto stageKV = [&](int skb, int pb) {
    if (doK) {
      int skc = skb + ksk; if (skc >= Sk) skc = Sk - 1;
      gload16(kp + (size_t)skc * kStride + kc * 32 + kqd * 8,
              &KsL[pb][ts * 8]);
    } else {
      gload16(vtp + (size_t)vd * vtStride + skb + vqd * 8,
              &VTsL[pb][ts * 8]);
    }
  };

  const int NITa = (Sk + 31) >> 5;
  stageKV(0, 0);
  if (NITa > 1) stageKV(32, 1);

  int cur = 0, pre = 2;
  int it = 0;
  for (int skb = 0; skb < Sk; skb += 32, ++it) {
    if (it + 1 < NITa) wait_vmcnt<1>();
    else wait_vmcnt<0>();
    __builtin_amdgcn_s_barrier();
    __builtin_amdgcn_sched_barrier(0);

    const bool tail = (skb + 32 > Sk);
    #pragma unroll
    for (int ct = 0; ct < 2; ct++) {
      f32x4 s = zero4;
      half8 kb0 = *(const half8*)(&KsL[cur][(quad * 32 + ct * 16 + l15) * 8]);
      half8 kb1 =
          *(const half8*)(&KsL[cur][(128 + quad * 32 + ct * 16 + l15) * 8]);
      s = mfma16(qf[0], kb0, s);
      s = mfma16(qf[1], kb1, s);
      if (tail) {
        const bool valid = (skb + ct * 16 + l15) < Sk;
        #pragma unroll
        for (int r = 0; r < 4; r++)
          if (!valid) s[r] = -__builtin_inff();
      }
      #pragma unroll
      for (int r = 0; r < 4; r++) {
        const float e = exp2f(s[r]);
        psum[r] += e;
        Ps[w][quad * 4 + r][ct * 16 + l15] = (_Float16)e;
      }
    }
    {
      const half8 pf = *(const half8*)(&Ps[w][l15][quad * 8]);
      #pragma unroll
      for (int nt = 0; nt < 4; nt++) {
        const half8 vf =
            *(const half8*)(&VTsL[cur][(quad * 64 + nt * 16 + l15) * 8]);
        oa[nt] = mfma16(pf, vf, oa[nt]);
      }
    }

    asm volatile("s_waitcnt lgkmcnt(0)" ::: "memory");
    __builtin_amdgcn_sched_barrier(0);
    __builtin_amdgcn_s_barrier();
    if (it + 2 < NITa) stageKV(skb + 64, pre);
    cur = (cur == 2) ? 0 : cur + 1;
    pre = (pre == 2) ? 0 : pre + 1;
  }

  #pragma unroll
  for (int r = 0; r < 4; r++) {
    #pragma unroll
    for (int mm = 1; mm < 16; mm <<= 1)
      psum[r] += __shfl_xor(psum[r], mm);
    psum[r] = 1.0f / psum[r];
  }

  #pragma unroll
  for (int nt = 0; nt < 4; nt++)
    #pragma unroll
    for (int r = 0; r < 4; r++) {
      const size_t row = (size_t)(b * 1024 + q0 + quad * 4 + r);
      O[row * 512 + h * 64 + nt * 16 + l15] =
          (_Float16)(oa[nt][r] * psum[r]);
    }
}

// ---------------------------------------------------------------------------
extern "C" void kernel_launch(void* const* d_in, const int* in_sizes, int n_in,
                              void* d_out, int out_size, void* d_ws,
                              size_t ws_size, hipStream_t stream) {
  const float* x    = (const float*)d_in[0];
  const float* enc  = (const float*)d_in[1];
  const float* ln1g = (const float*)d_in[2];
  const float* ln1b = (const float*)d_in[3];
  const float* wq1  = (const float*)d_in[4];
  const float* wk1  = (const float*)d_in[5];
  const float* wv1  = (const float*)d_in[6];
  const float* wo1  = (const float*)d_in[7];
  const float* bo1  = (const float*)d_in[8];
  const float* ln2g = (const float*)d_in[9];
  const float* ln2b = (const float*)d_in[10];
  const float* wq2  = (const float*)d_in[11];
  const float* wk2  = (const float*)d_in[12];
  const float* wv2  = (const float*)d_in[13];
  const float* wo2  = (const float*)d_in[14];
  const float* bo2  = (const float*)d_in[15];
  const float* ln3g = (const float*)d_in[16];
  const float* ln3b = (const float*)d_in[17];
  const float* wg   = (const float*)d_in[18];
  const float* bg   = (const float*)d_in[19];
  const float* wf   = (const float*)d_in[20];
  const float* bfp  = (const float*)d_in[21];
  float* out = (float*)d_out;

  char* ws = (char*)d_ws;
  _Float16* qkvT  = (_Float16*)(ws + 0);         // [1536,512]
  _Float16* q2T   = (_Float16*)(ws + 1572864);   // [512,512]
  _Float16* kv2T  = (_Float16*)(ws + 2097152);   // [1024,768]
  _Float16* wo1T  = (_Float16*)(ws + 3670016);   // [512,512]
  _Float16* wo2T  = (_Float16*)(ws + 4194304);   // [512,512]
  _Float16* wgT   = (_Float16*)(ws + 4718592);   // [4096,512]
  _Float16* wfT   = (_Float16*)(ws + 8912896);   // [512,2048]
  _Float16* hbuf  = (_Float16*)(ws + 11010048);  // [8192,512] (VTself in attn1)
  _Float16* qkv   = (_Float16*)(ws + 19398656);  // [8192,1536]
  _Float16* q2b   = (_Float16*)(ws + 44564480);  // [8192,512]
  _Float16* kv2b  = (_Float16*)(ws + 52953088);  // [616,1024]
  _Float16* attnb = (_Float16*)(ws + 54214656);  // [8192,512]
  _Float16* ench  = (_Float16*)(ws + 62603264);  // [616,768]
  _Float16* ffb   = (_Float16*)(ws + 19398656);  // [8192,2048] aliases qkv+q2b
  _Float16* VTself = hbuf;                       // [4096,1024]
  _Float16* VTc   = (_Float16*)(ws + 62603264);  // [4096,96] over ench (dead
                                                 // after kv2 GEMM)

  // ---- fused prep: weights + enc + LN1 (one launch) ----
  PrepArgs pa;
  const float* srcs[10] = {wq1, wk1, wv1, wo1, wq2, wk2, wv2, wo2, wg, wf};
  _Float16* dsts[10] = {qkvT, qkvT + 512 * 512, qkvT + 1024 * 512, wo1T, q2T,
                        kv2T, kv2T + 512 * 768, wo2T, wgT, wfT};
  const int Ks[10] = {512, 512, 512, 512, 512, 768, 768, 512, 512, 2048};
  const int Ns[10] = {512, 512, 512, 512, 512, 512, 512, 512, 4096, 512};
  int base = 0;
  for (int i = 0; i < 10; i++) {
    pa.src[i] = srcs[i]; pa.dst[i] = dsts[i];
    pa.K[i] = Ks[i]; pa.N[i] = Ns[i]; pa.base[i] = base;
    base += (Ks[i] >> 5) * (Ns[i] >> 5);
  }
  pa.enc = enc; pa.ench = ench; pa.encBase = base; pa.nEnc = 473088;
  base += (473088 + 255) / 256;
  pa.x = x; pa.ln1g = ln1g; pa.ln1b = ln1b; pa.hbuf = hbuf; pa.lnBase = base;
  base += 8192;
  prep_all<<<base, dim3(32, 8), 0, stream>>>(pa);

  const dim3 tb(32, 8);

  // ---- self-attention block ----
  // QKV: 128x128 tile, 8 waves, grid 768 (R16)
  gemm_bt<0, 2, 4, 4, 2, 4, 1, 0><<<768, 512, 0, stream>>>(
      hbuf, qkvT, 8192, 1536, 512, 512, 512, 1536,
      qkv, nullptr, nullptr, nullptr);
  vt_kernel<<<dim3(32, 2, 64), tb, 0, stream>>>(qkv + 1024, VTself, 1024,
                                                1536, 1024);
  attn2<<<dim3(8, 64), 512, 0, stream>>>(qkv, qkv + 512, VTself, attnb,
                                         1536, 1536, (long)1024 * 1536,
                                         1024, 1024);
  // wo1: 64x128 tile, 16 waves, grid 512 -> 32 waves/CU (R17)
  gemm_bt<1, 4, 4, 1, 2, 8, 1, 0><<<512, 1024, 0, stream>>>(
      attnb, wo1T, 8192, 512, 512, 512, 512, 512, nullptr, out, bo1, x);

  // ---- cross-attention block ----
  ln_kernel<<<8192, 256, 0, stream>>>(out, ln2g, ln2b, hbuf);
  // q2 + kv2 merged (R18): 512 + 80 blocks, kv2 overlapped under q2
  gemm_q2kv2<<<592, 1024, 0, stream>>>(hbuf, q2T, q2b, ench, kv2T, kv2b);
  vt_kernel<<<dim3(3, 2, 64), tb, 0, stream>>>(kv2b + 512, VTc, 77, 1024, 96);
  attn2<<<dim3(8, 64), 512, 0, stream>>>(q2b, kv2b, VTc, attnb,
                                         512, 1024, (long)77 * 1024, 96, 77);
  gemm_bt<1, 4, 4, 1, 2, 8, 1, 0><<<512, 1024, 0, stream>>>(
      attnb, wo2T, 8192, 512, 512, 512, 512, 512, nullptr, out, bo2, out);

  // ---- GEGLU feed-forward ----
  ln_kernel<<<8192, 256, 0, stream>>>(out, ln3g, ln3b, hbuf);
  // GEGLU: 128x128-dual, 8 waves (R14 config) + tanh-GELU epilogue (R18)
  gemm_bt<2, 2, 4, 4, 2, 4, 1, 0><<<1024, 512, 0, stream>>>(
      hbuf, wgT, 8192, 2048, 512, 512, 512, 2048,
      ffb, nullptr, bg, nullptr);
  // wf: 64x128 tile, 16 waves, grid 512 -> 32 waves/CU (R17)
  gemm_bt<1, 4, 4, 1, 2, 8, 1, 0><<<512, 1024, 0, stream>>>(
      ffb, wfT, 8192, 512, 2048, 2048, 2048, 512,
      nullptr, out, bfp, out);
}